// Round 15
// baseline (140.386 us; speedup 1.0000x reference)
//
#include <hip/hip_runtime.h>
#include <hip/hip_bf16.h>
#include <math.h>

#define V_N 4096
#define E_N 2048
#define F_N 512
#define H_N 256

typedef unsigned short u16;
typedef unsigned char u8;
typedef unsigned long long ull;
typedef __attribute__((ext_vector_type(8))) short short8;
typedef __attribute__((ext_vector_type(4))) float f32x4;

union S8L2 { short8 s; long l[2]; };

__device__ __forceinline__ float bf2f(u16 u) {
  union { float f; unsigned int q; } x; x.q = ((unsigned int)u) << 16; return x.f;
}
__device__ __forceinline__ u16 f2bf(float f) {
  union { float f; unsigned int q; } x; x.f = f;
  unsigned int q = x.q + 0x7FFFu + ((x.q >> 16) & 1u);
  return (u16)(q >> 16);
}

__device__ __forceinline__ void gload16(const void* g, void* l) {
  __builtin_amdgcn_global_load_lds((const __attribute__((address_space(1))) void*)g,
                                   (__attribute__((address_space(3))) void*)l,
                                   16, 0, 0);
}

__device__ __forceinline__ float theta_of(int n_) {
  float n = (float)n_;
  return 1.f - (1.f - 0.01f) * (cosf(3.14159265358979f * (n - 1.f) / 10.f) + 1.f) * 0.5f;
}

// pack 8 f32 -> 8 fp8 e4m3 (bytes k0..k0+7 ascending)
__device__ __forceinline__ ull pack8_fp8(const float* p) {
  int w0 = __builtin_amdgcn_cvt_pk_fp8_f32(p[0], p[1], 0, false);
  w0 = __builtin_amdgcn_cvt_pk_fp8_f32(p[2], p[3], w0, true);
  int w1 = __builtin_amdgcn_cvt_pk_fp8_f32(p[4], p[5], 0, false);
  w1 = __builtin_amdgcn_cvt_pk_fp8_f32(p[6], p[7], w1, true);
  return (ull)(unsigned int)w0 | ((ull)(unsigned int)w1 << 32);
}

// pi-permuted byte position of an 8-aligned k-chunk within a row
__device__ __forceinline__ int pi8(int k0) {
  return (k0 & ~63) + (((k0 >> 3) & 3) << 4) + (((k0 >> 5) & 1) << 3);
}

// =================== 256x256 8-phase fp8 NT GEMM (T1+T2+T3+T4+T5) ============
// Zero-conflict LDS geometry (proven round 6). See prior rounds.

#define BARX do { asm volatile("" ::: "memory"); __builtin_amdgcn_s_barrier(); \
                  asm volatile("" ::: "memory"); } while (0)

#define LDA_Q8(buf, mh_) do { \
  _Pragma("unroll") \
  for (int m_ = 0; m_ < 4; ++m_) { \
    int L_ = (wr << 6) + m_ * 16 + (lane & 15); \
    int s_ = (((mh_) << 2) | (lane >> 4)) ^ (lane & 7); \
    S8L2 u_; u_.s = *(const short8*)((buf) + L_ * 128 + s_ * 16); \
    a0[m_] = u_.l[0]; a1[m_] = u_.l[1]; \
  } \
} while (0)

#define LDB_Q8(buf, nh_) do { \
  _Pragma("unroll") \
  for (int n_ = 0; n_ < 2; ++n_) { \
    int L_ = (wc << 5) + n_ * 16 + (lane & 15); \
    int s_ = (((nh_) << 2) | (lane >> 4)) ^ (lane & 7); \
    S8L2 u_; u_.s = *(const short8*)((buf) + L_ * 128 + s_ * 16); \
    b0[(nh_) * 2 + n_] = u_.l[0]; b1[(nh_) * 2 + n_] = u_.l[1]; \
  } \
} while (0)

#define MMA_Q8(mh_, nh_) do { \
  __builtin_amdgcn_s_setprio(1); \
  _Pragma("unroll") \
  for (int m_ = 0; m_ < 4; ++m_) { \
    _Pragma("unroll") \
    for (int n_ = 0; n_ < 2; ++n_) { \
      acc[(mh_) * 4 + m_][(nh_) * 2 + n_] = __builtin_amdgcn_mfma_f32_16x16x32_fp8_fp8( \
          a0[m_], b0[(nh_) * 2 + n_], acc[(mh_) * 4 + m_][(nh_) * 2 + n_], 0, 0, 0); \
      acc[(mh_) * 4 + m_][(nh_) * 2 + n_] = __builtin_amdgcn_mfma_f32_16x16x32_fp8_fp8( \
          a1[m_], b1[(nh_) * 2 + n_], acc[(mh_) * 4 + m_][(nh_) * 2 + n_], 0, 0, 0); \
    } } \
  __builtin_amdgcn_s_setprio(0); \
} while (0)

template<int TILE>
__device__ __forceinline__ void stage_half8(const u8* __restrict__ g, int K, int kt,
                                            u8* lds, int tid, int hh) {
  int L  = hh * 64 + (tid >> 3);
  int su = (tid & 7) ^ (L & 7);
  int hr = su >> 2, gc = su & 3;
  int R;
  if constexpr (TILE == 0) R = (L & 63) + ((L >> 6) << 7) + (hr << 6);
  else                     R = (L & 31) + ((L >> 5) << 6) + (hr << 5);
  gload16(g + (size_t)R * K + kt + (gc << 4), lds + hh * 8192 + (tid << 4));
}

// scores-exp: outB = bf16(exp(acc*scale)); fused DVo[row] += rowsum
__global__ __launch_bounds__(512, 2)
void gemm_nt_big8(const u8* __restrict__ A, const u8* __restrict__ B,
                  int N, int K, float scale,
                  u16* __restrict__ outB,
                  float* __restrict__ DVo)
{
  extern __shared__ __align__(16) u8 lds8[];
  u8* As0 = lds8;
  u8* Bs0 = lds8 + 16384;
  u8* As1 = lds8 + 32768;
  u8* Bs1 = lds8 + 49152;

  const int tid = threadIdx.x, lane = tid & 63, wave = tid >> 6;
  const int wr = wave >> 2, wc = wave & 3;

  const int nwg = gridDim.x * gridDim.y;
  const int lin = blockIdx.y * gridDim.x + blockIdx.x;
  const int swz = (lin & 7) * (nwg >> 3) + (lin >> 3);
  const int bx = swz % gridDim.x, by = swz / gridDim.x;
  const int tileM = by * 256, tileN = bx * 256;

  const u8* Ag = A + (size_t)tileM * K;
  const u8* Bg = B + (size_t)tileN * K;
  const int NT = K / 64;

  f32x4 acc[8][4] = {};
  long a0[4], a1[4], b0[8], b1[8];

  stage_half8<0>(Ag, K, 0, As0, tid, 0);
  stage_half8<0>(Ag, K, 0, As0, tid, 1);
  stage_half8<1>(Bg, K, 0, Bs0, tid, 0);
  stage_half8<1>(Bg, K, 0, Bs0, tid, 1);
  stage_half8<0>(Ag, K, 64, As1, tid, 0);
  stage_half8<1>(Bg, K, 64, Bs1, tid, 0);
  asm volatile("s_waitcnt vmcnt(2)" ::: "memory");
  BARX;

  for (int it = 0; it < NT / 2; ++it) {
    const int t = it * 2;
    const int k1 = (t + 1) * 64, k2 = (t + 2) * 64, k3 = (t + 3) * 64;
    const bool h2 = (t + 2) < NT;
    LDA_Q8(As0, 0); LDB_Q8(Bs0, 0);
    stage_half8<0>(Ag, K, k1, As1, tid, 1);
    BARX; MMA_Q8(0, 0); BARX;

    LDB_Q8(Bs0, 1);
    stage_half8<1>(Bg, K, k1, Bs1, tid, 1);
    BARX; MMA_Q8(0, 1); BARX;

    LDA_Q8(As0, 1);
    if (h2) stage_half8<0>(Ag, K, k2, As0, tid, 0);
    BARX; MMA_Q8(1, 0); BARX;

    if (h2) {
      stage_half8<1>(Bg, K, k2, Bs0, tid, 0);
      asm volatile("s_waitcnt vmcnt(2)" ::: "memory");
    } else {
      asm volatile("s_waitcnt vmcnt(0)" ::: "memory");
    }
    BARX; MMA_Q8(1, 1); BARX;

    LDA_Q8(As1, 0); LDB_Q8(Bs1, 0);
    if (h2) stage_half8<0>(Ag, K, k2, As0, tid, 1);
    BARX; MMA_Q8(0, 0); BARX;

    LDB_Q8(Bs1, 1);
    if (h2) stage_half8<1>(Bg, K, k2, Bs0, tid, 1);
    BARX; MMA_Q8(0, 1); BARX;

    LDA_Q8(As1, 1);
    if (h2) stage_half8<0>(Ag, K, k3, As1, tid, 0);
    BARX; MMA_Q8(1, 0); BARX;

    if (h2) {
      stage_half8<1>(Bg, K, k3, Bs1, tid, 0);
      asm volatile("s_waitcnt vmcnt(2)" ::: "memory");
    } else {
      asm volatile("s_waitcnt vmcnt(0)" ::: "memory");
    }
    BARX; MMA_Q8(1, 1); BARX;
  }

  const int r0 = tileM + wr * 128 + ((lane >> 4) << 2);
  const int c0 = tileN + wc * 64 + (lane & 15);
#pragma unroll
  for (int m = 0; m < 8; ++m) {
#pragma unroll
    for (int j = 0; j < 4; ++j) {
      const int row = r0 + m * 16 + j;
      float rsum = 0.f;
#pragma unroll
      for (int n = 0; n < 4; ++n) {
        const int col = c0 + n * 16;
        float hv = __expf(acc[m][n][j] * scale);
        outB[(size_t)row * N + col] = f2bf(hv);
        rsum += hv;
      }
      rsum += __shfl_xor(rsum, 1); rsum += __shfl_xor(rsum, 2);
      rsum += __shfl_xor(rsum, 4); rsum += __shfl_xor(rsum, 8);
      if ((lane & 15) == 0) atomicAdd(&DVo[row], rsum);
    }
  }
}

// =================== 128x128 bf16 MFMA NT GEMM (skinny shapes) ===============
// XOR-swizzled LDS. EPI 1 = full bf16 store; EPI 2 = bf16 SLICE store.
#define BM 128
#define BN 128
#define BK 64

template<int EPI>
__global__ __launch_bounds__(256)
void gemm_nt(const u16* __restrict__ A, const u16* __restrict__ B,
             int M, int N, int K, int ksplit, size_t sstride,
             u16* __restrict__ outB)
{
  __shared__ __align__(16) u16 As[BM * BK];
  __shared__ __align__(16) u16 Bs[BN * BK];
  const int tid  = threadIdx.x;
  const int lane = tid & 63;
  const int wave = tid >> 6;
  const int wr = wave >> 1, wc = wave & 1;

  int bxx = blockIdx.x, byy = blockIdx.y, bzz = blockIdx.z;
  if (gridDim.x == 2) {
    int lin = bxx + 2 * (byy + gridDim.y * bzz);
    bxx = (lin >> 3) & 1;
    int q = (lin & 7) | ((lin >> 4) << 3);
    byy = q % gridDim.y;
    bzz = q / gridDim.y;
  }
  const int tileM = byy * BM;
  const int tileN = bxx * BN;
  const int kper = K / ksplit;
  const int kbeg = bzz * kper;
  const int kend = kbeg + kper;

  const int srow = wave * 8 + (lane >> 3);
  const int sdst = (lane & 7) * 8;
  const int ssrc = ((lane & 7) ^ (lane >> 3)) * 8;

  f32x4 acc[4][4] = {};

  const u16* Arow = A + (size_t)tileM * K;
  const u16* Brow = B + (size_t)tileN * K;

  for (int kt = kbeg; kt < kend; kt += BK) {
    __syncthreads();
#pragma unroll
    for (int r = 0; r < 4; ++r) {
      int row = r * 32 + srow;
      gload16(Arow + (size_t)row * K + kt + ssrc, &As[row * BK + sdst]);
      gload16(Brow + (size_t)row * K + kt + ssrc, &Bs[row * BK + sdst]);
    }
    __syncthreads();
#pragma unroll
    for (int ks = 0; ks < 2; ++ks) {
      short8 af[4], bfq[4];
#pragma unroll
      for (int m = 0; m < 4; ++m)
        af[m] = *(const short8*)&As[(wr * 64 + m * 16 + (lane & 15)) * BK
                 + ((((ks << 2) | (lane >> 4)) ^ (lane & 7)) << 3)];
#pragma unroll
      for (int n = 0; n < 4; ++n)
        bfq[n] = *(const short8*)&Bs[(wc * 64 + n * 16 + (lane & 15)) * BK
                 + ((((ks << 2) | (lane >> 4)) ^ (lane & 7)) << 3)];
#pragma unroll
      for (int m = 0; m < 4; ++m)
#pragma unroll
        for (int n = 0; n < 4; ++n)
          acc[m][n] = __builtin_amdgcn_mfma_f32_16x16x32_bf16(af[m], bfq[n], acc[m][n], 0, 0, 0);
    }
  }

  const int r0 = tileM + wr * 64 + ((lane >> 4) << 2);
  const int c0 = tileN + wc * 64 + (lane & 15);
  u16* oB = (EPI == 2) ? (outB + (size_t)bzz * sstride) : outB;
#pragma unroll
  for (int m = 0; m < 4; ++m) {
#pragma unroll
    for (int j = 0; j < 4; ++j) {
      const int row = r0 + m * 16 + j;
#pragma unroll
      for (int n = 0; n < 4; ++n) {
        const int col = c0 + n * 16;
        oB[(size_t)row * N + col] = f2bf(acc[m][n][j]);
      }
    }
  }
}

// ---------------- utility kernels ----------------

// merged prep: blocks 0..8191 = adj transpose + column-degree;
// 8192..10239 = feats->bf16; 10240..11263 = Wcat transpose->bf16
__global__ void k_prep(const float* __restrict__ adj, const float* __restrict__ feats,
                       const float* __restrict__ Wl, const float* __restrict__ Wv,
                       u16* __restrict__ adjT, float* __restrict__ deg,
                       u16* __restrict__ featsb, u16* __restrict__ WT) {
  __shared__ float t[32][33];
  int bx = blockIdx.x;
  if (bx < 8192) {
    int e0 = (bx & 63) * 32, v0 = (bx >> 6) * 32;
    int tx = threadIdx.x & 31, ty = threadIdx.x >> 5;
    for (int i = ty; i < 32; i += 8)
      t[i][tx] = adj[(size_t)(v0 + i) * E_N + e0 + tx];
    __syncthreads();
    for (int i = ty; i < 32; i += 8)
      adjT[(size_t)(e0 + i) * V_N + v0 + tx] = f2bf(t[tx][i]);
    if (ty == 0) {
      float s = 0.f;
#pragma unroll
      for (int i = 0; i < 32; ++i) s += t[i][tx];
      atomicAdd(&deg[e0 + tx], s);
    }
  } else if (bx < 10240) {
    int i = (bx - 8192) * 256 + threadIdx.x;
    float4 v = ((const float4*)feats)[i];
    ushort4 o; o.x = f2bf(v.x); o.y = f2bf(v.y); o.z = f2bf(v.z); o.w = f2bf(v.w);
    ((ushort4*)featsb)[i] = o;
  } else {
    int id = (bx - 10240) * 256 + threadIdx.x;
    int n = id >> 9, k = id & 511;
    float v = (n < 256) ? Wl[(size_t)k * 256 + n] : Wv[(size_t)k * 256 + (n - 256)];
    WT[id] = f2bf(v);
  }
}

// fwcatb (V,512) bf16 -> fwlinT (256,V), fvT (256,V) + fused fp8-pi pack of fv
__global__ void k_splitfw(const u16* __restrict__ fw, u16* __restrict__ fwlinT,
                          u16* __restrict__ fvT, ull* __restrict__ fvb8) {
  __shared__ u16 t[32][33];
  int h0 = blockIdx.x * 32, v0 = blockIdx.y * 32;
  int tx = threadIdx.x & 31, ty = threadIdx.x >> 5;
  for (int i = ty; i < 32; i += 8)
    t[i][tx] = fw[(size_t)(v0 + i) * 512 + h0 + tx];
  __syncthreads();
  u16* oT = (h0 < 256) ? fwlinT : fvT;
  int hb = (h0 < 256) ? h0 : h0 - 256;
  for (int i = ty; i < 32; i += 8)
    oT[(size_t)(hb + i) * V_N + v0 + tx] = t[tx][i];
  if (h0 >= 256 && threadIdx.x < 128) {
    int i = threadIdx.x >> 2, c = threadIdx.x & 3;
    int k0 = (h0 - 256) + c * 8;
    float f[8];
#pragma unroll
    for (int j = 0; j < 8; ++j) f[j] = bf2f(t[i][c * 8 + j]);
    fvb8[(size_t)(v0 + i) * 32 + (pi8(k0) >> 3)] = pack8_fp8(f);
  }
}

// Fused dual LayerNorm over bf16 slice sums (8 slices each path).
__global__ void k_ln8dual(const u16* __restrict__ XE8, const u16* __restrict__ XV8,
                          const float* __restrict__ deg, const float* __restrict__ rsumS,
                          const float* __restrict__ g1, const float* __restrict__ b1,
                          const float* __restrict__ g2, const float* __restrict__ b2,
                          const float* __restrict__ w,
                          u16* __restrict__ sw_b, u16* __restrict__ d_b,
                          float* __restrict__ aE, float* __restrict__ cV)
{
  __shared__ float sm[8];
  const int bid = blockIdx.x, tid = threadIdx.x, lane = tid & 63, wave = tid >> 6;
  const bool isE = bid < E_N;
  const int row = isE ? bid : bid - E_N;
  const u16* X = isE ? XE8 : XV8;
  const size_t sstr = isE ? (size_t)E_N * H_N : (size_t)V_N * H_N;
  const float* divv = isE ? deg : rsumS;
  const float* gg = isE ? g1 : g2;
  const float* bb = isE ? b1 : b2;
  u16* outB = isE ? sw_b : d_b;
  float* outA = isE ? aE : cV;

  float x = 0.f;
#pragma unroll
  for (int s = 0; s < 8; ++s)
    x += bf2f(X[(size_t)s * sstr + (size_t)row * 256 + tid]);
  x /= divv[row];
  float s1 = x, s2 = x * x;
#pragma unroll
  for (int o = 32; o > 0; o >>= 1) { s1 += __shfl_down(s1, o); s2 += __shfl_down(s2, o); }
  if (lane == 0) { sm[wave] = s1; sm[4 + wave] = s2; }
  __syncthreads();
  float sx  = sm[0] + sm[1] + sm[2] + sm[3];
  float sx2 = sm[4] + sm[5] + sm[6] + sm[7];
  float mu  = sx * (1.f / 256.f);
  float var = sx2 * (1.f / 256.f) - mu * mu;
  float rs  = rsqrtf(var + 1e-5f);
  float xln = (x - mu) * rs * gg[tid] + bb[tid];
  outB[(size_t)row * 256 + tid] = f2bf(isE ? xln * w[tid] : xln);
  float t = w[tid] * xln * xln;
  __syncthreads();
#pragma unroll
  for (int o = 32; o > 0; o >>= 1) t += __shfl_down(t, o);
  if (lane == 0) sm[wave] = t;
  __syncthreads();
  if (tid == 0) outA[row] = sm[0] + sm[1] + sm[2] + sm[3];
}

// H-stats, stage 1: D[h] = sum_v d[v][h], SW[h] = sum_e sw[e][h],
// sums[0] = sum aE, sums[1] = sum cV. (targets pre-zeroed)
__global__ void k_hstats(const u16* __restrict__ d_b, const u16* __restrict__ sw_b,
                         const float* __restrict__ aE, const float* __restrict__ cV,
                         float* __restrict__ D, float* __restrict__ SW,
                         float* __restrict__ sums) {
  int b = blockIdx.x, tid = threadIdx.x;
  if (b < 16) {
    float acc = 0.f;
    const u16* p = d_b + (size_t)b * 256 * 256 + tid;
    for (int r = 0; r < 256; ++r) acc += bf2f(p[r * 256]);
    atomicAdd(&D[tid], acc);
  } else if (b < 24) {
    float acc = 0.f;
    const u16* p = sw_b + (size_t)(b - 16) * 256 * 256 + tid;
    for (int r = 0; r < 256; ++r) acc += bf2f(p[r * 256]);
    atomicAdd(&SW[tid], acc);
  } else {
    const float* src = (b == 24) ? aE : cV;
    const int n = (b == 24) ? E_N : V_N;
    float s = 0.f;
    for (int i = tid; i < n; i += 256) s += src[i];
#pragma unroll
    for (int o = 32; o > 0; o >>= 1) s += __shfl_down(s, o);
    if ((tid & 63) == 0) atomicAdd(&sums[b - 24], s);
  }
}

// H-stats, stage 2 (linearized H): DV/DE + uv=rsqrt(DV), udv=sqrt(DV) vectors.
__global__ void k_dvde(const u16* __restrict__ d_b, const u16* __restrict__ sw_b,
                       const float* __restrict__ aE, const float* __restrict__ cV,
                       const float* __restrict__ D, const float* __restrict__ SW,
                       const float* __restrict__ sums, const float* __restrict__ biasp,
                       const int* __restrict__ sigmap,
                       float* __restrict__ DV, float* __restrict__ DE,
                       float* __restrict__ uv, float* __restrict__ udv) {
  __shared__ float sm[4];
  const int b = blockIdx.x, tid = threadIdx.x, lane = tid & 63, wave = tid >> 6;
  const bool isV = b < V_N;
  const int row = isV ? b : b - V_N;
  const u16* X = isV ? d_b : sw_b;
  const float* O = isV ? SW : D;
  float x = bf2f(X[(size_t)row * 256 + tid]) * O[tid];
#pragma unroll
  for (int o = 32; o > 0; o >>= 1) x += __shfl_down(x, o);
  if (lane == 0) sm[wave] = x;
  __syncthreads();
  if (tid == 0) {
    const float dot = sm[0] + sm[1] + sm[2] + sm[3];
    const float sgm = (float)sigmap[0];
    const float i2s = 1.f / (2.f * sgm * sgm);
    const float bias = biasp[0];
    if (isV) {
      float dv = (float)E_N - i2s * (sums[0] + (float)E_N * (cV[row] + bias) - 2.f * dot);
      DV[row] = dv;
      float u = rsqrtf(dv);
      uv[row] = u;
      udv[row] = u * dv;            // = sqrt(dv)
    } else {
      DE[row] = (float)V_N - i2s * ((float)V_N * (aE[row] + bias) + sums[1] - 2.f * dot);
    }
  }
}

// 1 block: S = sum_e 1/DE_e; scal[0] = 1-theta, scal[1] = theta*S/E_N
__global__ void k_sfin(const float* __restrict__ DE, const int* __restrict__ num,
                       float* __restrict__ scal) {
  __shared__ float sm[4];
  const int tid = threadIdx.x, lane = tid & 63, wave = tid >> 6;
  float s = 0.f;
#pragma unroll
  for (int e = 0; e < E_N / 256; ++e) s += 1.f / DE[e * 256 + tid];
#pragma unroll
  for (int o = 32; o > 0; o >>= 1) s += __shfl_down(s, o);
  if (lane == 0) sm[wave] = s;
  __syncthreads();
  if (tid == 0) {
    const float S = sm[0] + sm[1] + sm[2] + sm[3];
    const float theta = theta_of(num[0]);
    scal[0] = 1.f - theta;
    scal[1] = theta * S * (1.f / (float)E_N);
  }
}

// out[i,j] = scal0*G + C0*uv[j] + C1*udv[j];  C1 = scal1*uv_i, C0 = C1*(DV_i-E).
// 8 rows/block; uv/udv column chunks hoisted into registers BEFORE the row
// loop -> inner loop is 4 G-loads + 4 nt-stores per row (VMEM-issue dominated
// pattern: 16 -> 9 VMEM instrs per row-chunk).
__global__ __launch_bounds__(256)
void k_blend(const float* __restrict__ G, const float* __restrict__ DV,
             const float* __restrict__ uv, const float* __restrict__ udv,
             const float* __restrict__ scal, float* __restrict__ out) {
  const int tid = threadIdx.x;
  const float omt = scal[0], tk = scal[1];
  const int row0 = blockIdx.x * 8;

  // hoist column vectors (row-invariant): 8 f32x4 = 32 VGPR
  f32x4 uu[4], dd[4];
  const f32x4* u4 = (const f32x4*)uv;
  const f32x4* ud4 = (const f32x4*)udv;
#pragma unroll
  for (int c4 = 0; c4 < 4; ++c4) {
    uu[c4] = u4[c4 * 256 + tid];
    dd[c4] = ud4[c4 * 256 + tid];
  }

#pragma unroll
  for (int rr = 0; rr < 8; ++rr) {
    const int row = row0 + rr;
    const float uvi = uv[row];
    const float C1 = tk * uvi;
    const float C0 = C1 * (DV[row] - (float)E_N);
    const f32x4* g4 = (const f32x4*)(G + (size_t)row * V_N);
    f32x4* o4 = (f32x4*)(out + (size_t)row * V_N);
#pragma unroll
    for (int c4 = 0; c4 < 4; ++c4) {
      const int c = c4 * 256 + tid;
      f32x4 g = g4[c];
      f32x4 o;
      o.x = omt * g.x + C0 * uu[c4].x + C1 * dd[c4].x;
      o.y = omt * g.y + C0 * uu[c4].y + C1 * dd[c4].y;
      o.z = omt * g.z + C0 * uu[c4].z + C1 * dd[c4].z;
      o.w = omt * g.w + C0 * uu[c4].w + C1 * dd[c4].w;
      __builtin_nontemporal_store(o, &o4[c]);
    }
  }
}

// ---------------- host ----------------

extern "C" void kernel_launch(void* const* d_in, const int* in_sizes, int n_in,
                              void* d_out, int out_size, void* d_ws, size_t ws_size,
                              hipStream_t stream)
{
  const float* adj   = (const float*)d_in[0];
  const float* G     = (const float*)d_in[1];
  const float* feats = (const float*)d_in[2];
  const float* Wl    = (const float*)d_in[3];
  const float* Wv    = (const float*)d_in[4];
  const float* wo_w  = (const float*)d_in[5];
  const float* wo_b  = (const float*)d_in[6];
  const float* g1    = (const float*)d_in[7];
  const float* b1    = (const float*)d_in[8];
  const float* g2    = (const float*)d_in[9];
  const float* b2    = (const float*)d_in[10];
  const int*   num   = (const int*)d_in[11];
  const int*   sigma = (const int*)d_in[12];
  float* out = (float*)d_out;

  hipFuncSetAttribute((const void*)gemm_nt_big8, hipFuncAttributeMaxDynamicSharedMemorySize, 65536);

  char* w = (char*)d_ws;
  auto take = [&](size_t b) { void* p = (void*)w; w += (b + 255) & ~(size_t)255; return p; };
  // zero-region: deg, rsumS, D, SW, sums (contiguous, one memset)
  float* deg   = (float*)take(E_N * 4);
  float* rsumS = (float*)take(V_N * 4);
  float* Dv    = (float*)take(256 * 4);
  float* SWv   = (float*)take(256 * 4);
  float* sums  = (float*)take(256);
  // written-not-accumulated:
  float* aE    = (float*)take(E_N * 4);
  float* cV    = (float*)take(V_N * 4);
  float* DV    = (float*)take(V_N * 4);
  float* DE    = (float*)take(E_N * 4);
  float* uvv   = (float*)take(V_N * 4);
  float* udvv  = (float*)take(V_N * 4);
  float* scal  = (float*)take(256);
  // big0 (20.5 MB): featsb + WcatT + adjTb; later: d_mat8 (8 slices x V x H bf16 = 16 MB)
  char* big0   = (char*)take((size_t)V_N * F_N * 2 + 512 * 512 * 2 + (size_t)E_N * V_N * 2);
  u16* featsb  = (u16*)big0;
  u16* WcatT   = (u16*)(big0 + (size_t)V_N * F_N * 2);
  u16* adjTb   = (u16*)(big0 + (size_t)V_N * F_N * 2 + 512 * 512 * 2);
  u16* d_mat8  = (u16*)big0;
  // big1 (8.4 MB): fwcatb (4 MB) -> s_raw8 (8 slices x E x H bf16 = 8 MB)
  char* big1   = (char*)take((size_t)V_N * 512 * 4 + 256);
  u16* fwcatb  = (u16*)big1;
  u16* s_raw8  = (u16*)big1;
  u16* fwlinT  = (u16*)take((size_t)H_N * V_N * 2);
  u16* fvT     = (u16*)take((size_t)H_N * V_N * 2);
  ull* fvb8    = (ull*)take((size_t)V_N * H_N);
  u16* sw_b    = (u16*)take((size_t)E_N * H_N * 2);
  u16* d_b     = (u16*)take((size_t)V_N * H_N * 2);
  u16* expsb   = (u16*)take((size_t)V_N * V_N * 2);
  (void)in_sizes; (void)n_in; (void)out_size;
  if ((size_t)(w - (char*)d_ws) > ws_size) return;

  hipMemsetAsync(deg, 0, (size_t)(E_N + V_N + 256 + 256 + 64) * 4, stream);

  // prep: adj transpose+deg, feats->bf16, Wcat transpose (one launch)
  k_prep<<<11264, 256, 0, stream>>>(adj, feats, Wl, Wv, adjTb, deg, featsb, WcatT);

  // G1: fwcatb = bf16(feats @ [W_lin|W_v])   (M=V, N=512, K=512)
  gemm_nt<1><<<dim3(512 / BN, V_N / BM), 256, 0, stream>>>(
      featsb, WcatT, V_N, 512, 512, 1, 0, fwcatb);
  k_splitfw<<<dim3(16, V_N / 32), 256, 0, stream>>>(fwcatb, fwlinT, fvT, fvb8);

  // G2: s_raw8 slices = adj.T @ fwlin   (M=E, N=H, K=V, split-K 8, bf16 slices)
  gemm_nt<2><<<dim3(H_N / BN, E_N / BM, 8), 256, 0, stream>>>(
      adjTb, fwlinT, E_N, H_N, V_N, 8, (size_t)E_N * H_N, s_raw8);

  // G3: expsb = exp(fv @ fv.T / 16)  (fp8 in, bf16 out) + fused row-sums
  gemm_nt_big8<<<dim3(V_N / 256, V_N / 256), 512, 65536, stream>>>(
      (const u8*)fvb8, (const u8*)fvb8, V_N, H_N, 0.0625f,
      expsb, rsumS);

  // G4: P slices = expS @ fv   (M=V, N=H, K=V, split-K 8, bf16 slices)
  gemm_nt<2><<<dim3(H_N / BN, V_N / BM, 8), 256, 0, stream>>>(
      expsb, fvT, V_N, H_N, V_N, 8, (size_t)V_N * H_N, d_mat8);

  // fused dual LayerNorm (E-rows: s-path -> sw_b/aE; V-rows: d-path -> d_b/cV)
  k_ln8dual<<<E_N + V_N, 256, 0, stream>>>(s_raw8, d_mat8, deg, rsumS,
                                           g1, b1, g2, b2, wo_w,
                                           sw_b, d_b, aE, cV);

  // linearized H statistics
  k_hstats<<<26, 256, 0, stream>>>(d_b, sw_b, aE, cV, Dv, SWv, sums);
  k_dvde<<<V_N + E_N, 256, 0, stream>>>(d_b, sw_b, aE, cV, Dv, SWv, sums,
                                        wo_b, sigma, DV, DE, uvv, udvv);
  k_sfin<<<1, 256, 0, stream>>>(DE, num, scal);

  // out = (1-theta)*G + theta*u_i*u_j*(S + t_i + t_j)  (rank-structure G6)
  k_blend<<<V_N / 8, 256, 0, stream>>>(G, DV, uvv, udvv, scal, out);
}

// Round 16
// 135.825 us; speedup vs baseline: 1.0336x; 1.0336x over previous
//
#include <hip/hip_runtime.h>
#include <hip/hip_bf16.h>
#include <math.h>

#define V_N 4096
#define E_N 2048
#define F_N 512
#define H_N 256

typedef unsigned short u16;
typedef unsigned char u8;
typedef unsigned long long ull;
typedef __attribute__((ext_vector_type(8))) short short8;
typedef __attribute__((ext_vector_type(4))) float f32x4;

union S8L2 { short8 s; long l[2]; };

__device__ __forceinline__ float bf2f(u16 u) {
  union { float f; unsigned int q; } x; x.q = ((unsigned int)u) << 16; return x.f;
}
__device__ __forceinline__ u16 f2bf(float f) {
  union { float f; unsigned int q; } x; x.f = f;
  unsigned int q = x.q + 0x7FFFu + ((x.q >> 16) & 1u);
  return (u16)(q >> 16);
}

__device__ __forceinline__ void gload16(const void* g, void* l) {
  __builtin_amdgcn_global_load_lds((const __attribute__((address_space(1))) void*)g,
                                   (__attribute__((address_space(3))) void*)l,
                                   16, 0, 0);
}

__device__ __forceinline__ float theta_of(int n_) {
  float n = (float)n_;
  return 1.f - (1.f - 0.01f) * (cosf(3.14159265358979f * (n - 1.f) / 10.f) + 1.f) * 0.5f;
}

// pack 8 f32 -> 8 fp8 e4m3 (bytes k0..k0+7 ascending)
__device__ __forceinline__ ull pack8_fp8(const float* p) {
  int w0 = __builtin_amdgcn_cvt_pk_fp8_f32(p[0], p[1], 0, false);
  w0 = __builtin_amdgcn_cvt_pk_fp8_f32(p[2], p[3], w0, true);
  int w1 = __builtin_amdgcn_cvt_pk_fp8_f32(p[4], p[5], 0, false);
  w1 = __builtin_amdgcn_cvt_pk_fp8_f32(p[6], p[7], w1, true);
  return (ull)(unsigned int)w0 | ((ull)(unsigned int)w1 << 32);
}

// pi-permuted byte position of an 8-aligned k-chunk within a row
__device__ __forceinline__ int pi8(int k0) {
  return (k0 & ~63) + (((k0 >> 3) & 3) << 4) + (((k0 >> 5) & 1) << 3);
}

// =================== 256x256 8-phase fp8 NT GEMM (T1+T2+T3+T4+T5) ============
// Zero-conflict LDS geometry (proven round 6). See prior rounds.

#define BARX do { asm volatile("" ::: "memory"); __builtin_amdgcn_s_barrier(); \
                  asm volatile("" ::: "memory"); } while (0)

#define LDA_Q8(buf, mh_) do { \
  _Pragma("unroll") \
  for (int m_ = 0; m_ < 4; ++m_) { \
    int L_ = (wr << 6) + m_ * 16 + (lane & 15); \
    int s_ = (((mh_) << 2) | (lane >> 4)) ^ (lane & 7); \
    S8L2 u_; u_.s = *(const short8*)((buf) + L_ * 128 + s_ * 16); \
    a0[m_] = u_.l[0]; a1[m_] = u_.l[1]; \
  } \
} while (0)

#define LDB_Q8(buf, nh_) do { \
  _Pragma("unroll") \
  for (int n_ = 0; n_ < 2; ++n_) { \
    int L_ = (wc << 5) + n_ * 16 + (lane & 15); \
    int s_ = (((nh_) << 2) | (lane >> 4)) ^ (lane & 7); \
    S8L2 u_; u_.s = *(const short8*)((buf) + L_ * 128 + s_ * 16); \
    b0[(nh_) * 2 + n_] = u_.l[0]; b1[(nh_) * 2 + n_] = u_.l[1]; \
  } \
} while (0)

#define MMA_Q8(mh_, nh_) do { \
  __builtin_amdgcn_s_setprio(1); \
  _Pragma("unroll") \
  for (int m_ = 0; m_ < 4; ++m_) { \
    _Pragma("unroll") \
    for (int n_ = 0; n_ < 2; ++n_) { \
      acc[(mh_) * 4 + m_][(nh_) * 2 + n_] = __builtin_amdgcn_mfma_f32_16x16x32_fp8_fp8( \
          a0[m_], b0[(nh_) * 2 + n_], acc[(mh_) * 4 + m_][(nh_) * 2 + n_], 0, 0, 0); \
      acc[(mh_) * 4 + m_][(nh_) * 2 + n_] = __builtin_amdgcn_mfma_f32_16x16x32_fp8_fp8( \
          a1[m_], b1[(nh_) * 2 + n_], acc[(mh_) * 4 + m_][(nh_) * 2 + n_], 0, 0, 0); \
    } } \
  __builtin_amdgcn_s_setprio(0); \
} while (0)

template<int TILE>
__device__ __forceinline__ void stage_half8(const u8* __restrict__ g, int K, int kt,
                                            u8* lds, int tid, int hh) {
  int L  = hh * 64 + (tid >> 3);
  int su = (tid & 7) ^ (L & 7);
  int hr = su >> 2, gc = su & 3;
  int R;
  if constexpr (TILE == 0) R = (L & 63) + ((L >> 6) << 7) + (hr << 6);
  else                     R = (L & 31) + ((L >> 5) << 6) + (hr << 5);
  gload16(g + (size_t)R * K + kt + (gc << 4), lds + hh * 8192 + (tid << 4));
}

// scores-exp: outB = bf16(exp(acc*scale)); fused DVo[row] += rowsum
__global__ __launch_bounds__(512, 2)
void gemm_nt_big8(const u8* __restrict__ A, const u8* __restrict__ B,
                  int N, int K, float scale,
                  u16* __restrict__ outB,
                  float* __restrict__ DVo)
{
  extern __shared__ __align__(16) u8 lds8[];
  u8* As0 = lds8;
  u8* Bs0 = lds8 + 16384;
  u8* As1 = lds8 + 32768;
  u8* Bs1 = lds8 + 49152;

  const int tid = threadIdx.x, lane = tid & 63, wave = tid >> 6;
  const int wr = wave >> 2, wc = wave & 3;

  const int nwg = gridDim.x * gridDim.y;
  const int lin = blockIdx.y * gridDim.x + blockIdx.x;
  const int swz = (lin & 7) * (nwg >> 3) + (lin >> 3);
  const int bx = swz % gridDim.x, by = swz / gridDim.x;
  const int tileM = by * 256, tileN = bx * 256;

  const u8* Ag = A + (size_t)tileM * K;
  const u8* Bg = B + (size_t)tileN * K;
  const int NT = K / 64;

  f32x4 acc[8][4] = {};
  long a0[4], a1[4], b0[8], b1[8];

  stage_half8<0>(Ag, K, 0, As0, tid, 0);
  stage_half8<0>(Ag, K, 0, As0, tid, 1);
  stage_half8<1>(Bg, K, 0, Bs0, tid, 0);
  stage_half8<1>(Bg, K, 0, Bs0, tid, 1);
  stage_half8<0>(Ag, K, 64, As1, tid, 0);
  stage_half8<1>(Bg, K, 64, Bs1, tid, 0);
  asm volatile("s_waitcnt vmcnt(2)" ::: "memory");
  BARX;

  for (int it = 0; it < NT / 2; ++it) {
    const int t = it * 2;
    const int k1 = (t + 1) * 64, k2 = (t + 2) * 64, k3 = (t + 3) * 64;
    const bool h2 = (t + 2) < NT;
    LDA_Q8(As0, 0); LDB_Q8(Bs0, 0);
    stage_half8<0>(Ag, K, k1, As1, tid, 1);
    BARX; MMA_Q8(0, 0); BARX;

    LDB_Q8(Bs0, 1);
    stage_half8<1>(Bg, K, k1, Bs1, tid, 1);
    BARX; MMA_Q8(0, 1); BARX;

    LDA_Q8(As0, 1);
    if (h2) stage_half8<0>(Ag, K, k2, As0, tid, 0);
    BARX; MMA_Q8(1, 0); BARX;

    if (h2) {
      stage_half8<1>(Bg, K, k2, Bs0, tid, 0);
      asm volatile("s_waitcnt vmcnt(2)" ::: "memory");
    } else {
      asm volatile("s_waitcnt vmcnt(0)" ::: "memory");
    }
    BARX; MMA_Q8(1, 1); BARX;

    LDA_Q8(As1, 0); LDB_Q8(Bs1, 0);
    if (h2) stage_half8<0>(Ag, K, k2, As0, tid, 1);
    BARX; MMA_Q8(0, 0); BARX;

    LDB_Q8(Bs1, 1);
    if (h2) stage_half8<1>(Bg, K, k2, Bs0, tid, 1);
    BARX; MMA_Q8(0, 1); BARX;

    LDA_Q8(As1, 1);
    if (h2) stage_half8<0>(Ag, K, k3, As1, tid, 0);
    BARX; MMA_Q8(1, 0); BARX;

    if (h2) {
      stage_half8<1>(Bg, K, k3, Bs1, tid, 0);
      asm volatile("s_waitcnt vmcnt(2)" ::: "memory");
    } else {
      asm volatile("s_waitcnt vmcnt(0)" ::: "memory");
    }
    BARX; MMA_Q8(1, 1); BARX;
  }

  const int r0 = tileM + wr * 128 + ((lane >> 4) << 2);
  const int c0 = tileN + wc * 64 + (lane & 15);
#pragma unroll
  for (int m = 0; m < 8; ++m) {
#pragma unroll
    for (int j = 0; j < 4; ++j) {
      const int row = r0 + m * 16 + j;
      float rsum = 0.f;
#pragma unroll
      for (int n = 0; n < 4; ++n) {
        const int col = c0 + n * 16;
        float hv = __expf(acc[m][n][j] * scale);
        outB[(size_t)row * N + col] = f2bf(hv);
        rsum += hv;
      }
      rsum += __shfl_xor(rsum, 1); rsum += __shfl_xor(rsum, 2);
      rsum += __shfl_xor(rsum, 4); rsum += __shfl_xor(rsum, 8);
      if ((lane & 15) == 0) atomicAdd(&DVo[row], rsum);
    }
  }
}

// =================== 128x128 bf16 MFMA NT GEMM (skinny shapes) ===============
// XOR-swizzled LDS. EPI 1 = full bf16 store; EPI 2 = bf16 SLICE store.
#define BM 128
#define BN 128
#define BK 64

template<int EPI>
__global__ __launch_bounds__(256)
void gemm_nt(const u16* __restrict__ A, const u16* __restrict__ B,
             int M, int N, int K, int ksplit, size_t sstride,
             u16* __restrict__ outB)
{
  __shared__ __align__(16) u16 As[BM * BK];
  __shared__ __align__(16) u16 Bs[BN * BK];
  const int tid  = threadIdx.x;
  const int lane = tid & 63;
  const int wave = tid >> 6;
  const int wr = wave >> 1, wc = wave & 1;

  int bxx = blockIdx.x, byy = blockIdx.y, bzz = blockIdx.z;
  if (gridDim.x == 2) {
    int lin = bxx + 2 * (byy + gridDim.y * bzz);
    bxx = (lin >> 3) & 1;
    int q = (lin & 7) | ((lin >> 4) << 3);
    byy = q % gridDim.y;
    bzz = q / gridDim.y;
  }
  const int tileM = byy * BM;
  const int tileN = bxx * BN;
  const int kper = K / ksplit;
  const int kbeg = bzz * kper;
  const int kend = kbeg + kper;

  const int srow = wave * 8 + (lane >> 3);
  const int sdst = (lane & 7) * 8;
  const int ssrc = ((lane & 7) ^ (lane >> 3)) * 8;

  f32x4 acc[4][4] = {};

  const u16* Arow = A + (size_t)tileM * K;
  const u16* Brow = B + (size_t)tileN * K;

  for (int kt = kbeg; kt < kend; kt += BK) {
    __syncthreads();
#pragma unroll
    for (int r = 0; r < 4; ++r) {
      int row = r * 32 + srow;
      gload16(Arow + (size_t)row * K + kt + ssrc, &As[row * BK + sdst]);
      gload16(Brow + (size_t)row * K + kt + ssrc, &Bs[row * BK + sdst]);
    }
    __syncthreads();
#pragma unroll
    for (int ks = 0; ks < 2; ++ks) {
      short8 af[4], bfq[4];
#pragma unroll
      for (int m = 0; m < 4; ++m)
        af[m] = *(const short8*)&As[(wr * 64 + m * 16 + (lane & 15)) * BK
                 + ((((ks << 2) | (lane >> 4)) ^ (lane & 7)) << 3)];
#pragma unroll
      for (int n = 0; n < 4; ++n)
        bfq[n] = *(const short8*)&Bs[(wc * 64 + n * 16 + (lane & 15)) * BK
                 + ((((ks << 2) | (lane >> 4)) ^ (lane & 7)) << 3)];
#pragma unroll
      for (int m = 0; m < 4; ++m)
#pragma unroll
        for (int n = 0; n < 4; ++n)
          acc[m][n] = __builtin_amdgcn_mfma_f32_16x16x32_bf16(af[m], bfq[n], acc[m][n], 0, 0, 0);
    }
  }

  const int r0 = tileM + wr * 64 + ((lane >> 4) << 2);
  const int c0 = tileN + wc * 64 + (lane & 15);
  u16* oB = (EPI == 2) ? (outB + (size_t)bzz * sstride) : outB;
#pragma unroll
  for (int m = 0; m < 4; ++m) {
#pragma unroll
    for (int j = 0; j < 4; ++j) {
      const int row = r0 + m * 16 + j;
#pragma unroll
      for (int n = 0; n < 4; ++n) {
        const int col = c0 + n * 16;
        oB[(size_t)row * N + col] = f2bf(acc[m][n][j]);
      }
    }
  }
}

// ---------------- utility kernels ----------------

// zero the accumulation region (replaces hipMemsetAsync: blit path has a
// ~39us fixed floor inside captured graphs; a plain kernel node is ~2-4us)
#define NZERO (E_N + V_N + 256 + 256 + 64)
__global__ void k_zero(float* __restrict__ p) {
  int i = blockIdx.x * 256 + threadIdx.x;
  if (i < NZERO / 4) ((f32x4*)p)[i] = (f32x4){0.f, 0.f, 0.f, 0.f};
}

// merged prep: blocks 0..8191 = adj transpose + column-degree;
// 8192..10239 = feats->bf16; 10240..11263 = Wcat transpose->bf16
__global__ void k_prep(const float* __restrict__ adj, const float* __restrict__ feats,
                       const float* __restrict__ Wl, const float* __restrict__ Wv,
                       u16* __restrict__ adjT, float* __restrict__ deg,
                       u16* __restrict__ featsb, u16* __restrict__ WT) {
  __shared__ float t[32][33];
  int bx = blockIdx.x;
  if (bx < 8192) {
    int e0 = (bx & 63) * 32, v0 = (bx >> 6) * 32;
    int tx = threadIdx.x & 31, ty = threadIdx.x >> 5;
    for (int i = ty; i < 32; i += 8)
      t[i][tx] = adj[(size_t)(v0 + i) * E_N + e0 + tx];
    __syncthreads();
    for (int i = ty; i < 32; i += 8)
      adjT[(size_t)(e0 + i) * V_N + v0 + tx] = f2bf(t[tx][i]);
    if (ty == 0) {
      float s = 0.f;
#pragma unroll
      for (int i = 0; i < 32; ++i) s += t[i][tx];
      atomicAdd(&deg[e0 + tx], s);
    }
  } else if (bx < 10240) {
    int i = (bx - 8192) * 256 + threadIdx.x;
    float4 v = ((const float4*)feats)[i];
    ushort4 o; o.x = f2bf(v.x); o.y = f2bf(v.y); o.z = f2bf(v.z); o.w = f2bf(v.w);
    ((ushort4*)featsb)[i] = o;
  } else {
    int id = (bx - 10240) * 256 + threadIdx.x;
    int n = id >> 9, k = id & 511;
    float v = (n < 256) ? Wl[(size_t)k * 256 + n] : Wv[(size_t)k * 256 + (n - 256)];
    WT[id] = f2bf(v);
  }
}

// fwcatb (V,512) bf16 -> fwlinT (256,V), fvT (256,V) + fused fp8-pi pack of fv
__global__ void k_splitfw(const u16* __restrict__ fw, u16* __restrict__ fwlinT,
                          u16* __restrict__ fvT, ull* __restrict__ fvb8) {
  __shared__ u16 t[32][33];
  int h0 = blockIdx.x * 32, v0 = blockIdx.y * 32;
  int tx = threadIdx.x & 31, ty = threadIdx.x >> 5;
  for (int i = ty; i < 32; i += 8)
    t[i][tx] = fw[(size_t)(v0 + i) * 512 + h0 + tx];
  __syncthreads();
  u16* oT = (h0 < 256) ? fwlinT : fvT;
  int hb = (h0 < 256) ? h0 : h0 - 256;
  for (int i = ty; i < 32; i += 8)
    oT[(size_t)(hb + i) * V_N + v0 + tx] = t[tx][i];
  if (h0 >= 256 && threadIdx.x < 128) {
    int i = threadIdx.x >> 2, c = threadIdx.x & 3;
    int k0 = (h0 - 256) + c * 8;
    float f[8];
#pragma unroll
    for (int j = 0; j < 8; ++j) f[j] = bf2f(t[i][c * 8 + j]);
    fvb8[(size_t)(v0 + i) * 32 + (pi8(k0) >> 3)] = pack8_fp8(f);
  }
}

// Fused dual LayerNorm over bf16 slice sums (8 slices each path).
__global__ void k_ln8dual(const u16* __restrict__ XE8, const u16* __restrict__ XV8,
                          const float* __restrict__ deg, const float* __restrict__ rsumS,
                          const float* __restrict__ g1, const float* __restrict__ b1,
                          const float* __restrict__ g2, const float* __restrict__ b2,
                          const float* __restrict__ w,
                          u16* __restrict__ sw_b, u16* __restrict__ d_b,
                          float* __restrict__ aE, float* __restrict__ cV)
{
  __shared__ float sm[8];
  const int bid = blockIdx.x, tid = threadIdx.x, lane = tid & 63, wave = tid >> 6;
  const bool isE = bid < E_N;
  const int row = isE ? bid : bid - E_N;
  const u16* X = isE ? XE8 : XV8;
  const size_t sstr = isE ? (size_t)E_N * H_N : (size_t)V_N * H_N;
  const float* divv = isE ? deg : rsumS;
  const float* gg = isE ? g1 : g2;
  const float* bb = isE ? b1 : b2;
  u16* outB = isE ? sw_b : d_b;
  float* outA = isE ? aE : cV;

  float x = 0.f;
#pragma unroll
  for (int s = 0; s < 8; ++s)
    x += bf2f(X[(size_t)s * sstr + (size_t)row * 256 + tid]);
  x /= divv[row];
  float s1 = x, s2 = x * x;
#pragma unroll
  for (int o = 32; o > 0; o >>= 1) { s1 += __shfl_down(s1, o); s2 += __shfl_down(s2, o); }
  if (lane == 0) { sm[wave] = s1; sm[4 + wave] = s2; }
  __syncthreads();
  float sx  = sm[0] + sm[1] + sm[2] + sm[3];
  float sx2 = sm[4] + sm[5] + sm[6] + sm[7];
  float mu  = sx * (1.f / 256.f);
  float var = sx2 * (1.f / 256.f) - mu * mu;
  float rs  = rsqrtf(var + 1e-5f);
  float xln = (x - mu) * rs * gg[tid] + bb[tid];
  outB[(size_t)row * 256 + tid] = f2bf(isE ? xln * w[tid] : xln);
  float t = w[tid] * xln * xln;
  __syncthreads();
#pragma unroll
  for (int o = 32; o > 0; o >>= 1) t += __shfl_down(t, o);
  if (lane == 0) sm[wave] = t;
  __syncthreads();
  if (tid == 0) outA[row] = sm[0] + sm[1] + sm[2] + sm[3];
}

// H-stats, stage 1: D[h] = sum_v d[v][h], SW[h] = sum_e sw[e][h],
// sums[0] = sum aE, sums[1] = sum cV. (targets pre-zeroed)
__global__ void k_hstats(const u16* __restrict__ d_b, const u16* __restrict__ sw_b,
                         const float* __restrict__ aE, const float* __restrict__ cV,
                         float* __restrict__ D, float* __restrict__ SW,
                         float* __restrict__ sums) {
  int b = blockIdx.x, tid = threadIdx.x;
  if (b < 16) {
    float acc = 0.f;
    const u16* p = d_b + (size_t)b * 256 * 256 + tid;
    for (int r = 0; r < 256; ++r) acc += bf2f(p[r * 256]);
    atomicAdd(&D[tid], acc);
  } else if (b < 24) {
    float acc = 0.f;
    const u16* p = sw_b + (size_t)(b - 16) * 256 * 256 + tid;
    for (int r = 0; r < 256; ++r) acc += bf2f(p[r * 256]);
    atomicAdd(&SW[tid], acc);
  } else {
    const float* src = (b == 24) ? aE : cV;
    const int n = (b == 24) ? E_N : V_N;
    float s = 0.f;
    for (int i = tid; i < n; i += 256) s += src[i];
#pragma unroll
    for (int o = 32; o > 0; o >>= 1) s += __shfl_down(s, o);
    if ((tid & 63) == 0) atomicAdd(&sums[b - 24], s);
  }
}

// H-stats, stage 2 (linearized H): blocks 0..V-1: DV/uv/udv per row.
// Block V: closed-form S (linearized 1/DE: S = E/V + (i2s/V^2)*T,
//  T = V*(sumA + E*bias) + E*sumC - 2*dot(SW,D)) and scal[] for k_blend.
__global__ void k_dvde(const u16* __restrict__ d_b,
                       const float* __restrict__ cV,
                       const float* __restrict__ D, const float* __restrict__ SW,
                       const float* __restrict__ sums, const float* __restrict__ biasp,
                       const int* __restrict__ sigmap, const int* __restrict__ num,
                       float* __restrict__ DV,
                       float* __restrict__ uv, float* __restrict__ udv,
                       float* __restrict__ scal) {
  __shared__ float sm[4];
  const int b = blockIdx.x, tid = threadIdx.x, lane = tid & 63, wave = tid >> 6;
  float x;
  if (b < V_N) {
    x = bf2f(d_b[(size_t)b * 256 + tid]) * SW[tid];
  } else {
    x = SW[tid] * D[tid];
  }
#pragma unroll
  for (int o = 32; o > 0; o >>= 1) x += __shfl_down(x, o);
  if (lane == 0) sm[wave] = x;
  __syncthreads();
  if (tid == 0) {
    const float dot = sm[0] + sm[1] + sm[2] + sm[3];
    const float sgm = (float)sigmap[0];
    const float i2s = 1.f / (2.f * sgm * sgm);
    const float bias = biasp[0];
    if (b < V_N) {
      float dv = (float)E_N - i2s * (sums[0] + (float)E_N * (cV[b] + bias) - 2.f * dot);
      DV[b] = dv;
      float u = rsqrtf(dv);
      uv[b] = u;
      udv[b] = u * dv;            // = sqrt(dv)
    } else {
      const float T = (float)V_N * (sums[0] + (float)E_N * bias)
                    + (float)E_N * sums[1] - 2.f * dot;
      const float S = (float)E_N / (float)V_N
                    + i2s * T / ((float)V_N * (float)V_N);
      const float theta = theta_of(num[0]);
      scal[0] = 1.f - theta;
      scal[1] = theta * S * (1.f / (float)E_N);
    }
  }
}

// out[i,j] = scal0*G + C0*uv[j] + C1*udv[j];  C1 = scal1*uv_i, C0 = C1*(DV_i-E).
// 8 rows/block; uv/udv column chunks hoisted into registers.
__global__ __launch_bounds__(256)
void k_blend(const float* __restrict__ G, const float* __restrict__ DV,
             const float* __restrict__ uv, const float* __restrict__ udv,
             const float* __restrict__ scal, float* __restrict__ out) {
  const int tid = threadIdx.x;
  const float omt = scal[0], tk = scal[1];
  const int row0 = blockIdx.x * 8;

  f32x4 uu[4], dd[4];
  const f32x4* u4 = (const f32x4*)uv;
  const f32x4* ud4 = (const f32x4*)udv;
#pragma unroll
  for (int c4 = 0; c4 < 4; ++c4) {
    uu[c4] = u4[c4 * 256 + tid];
    dd[c4] = ud4[c4 * 256 + tid];
  }

#pragma unroll
  for (int rr = 0; rr < 8; ++rr) {
    const int row = row0 + rr;
    const float uvi = uv[row];
    const float C1 = tk * uvi;
    const float C0 = C1 * (DV[row] - (float)E_N);
    const f32x4* g4 = (const f32x4*)(G + (size_t)row * V_N);
    f32x4* o4 = (f32x4*)(out + (size_t)row * V_N);
#pragma unroll
    for (int c4 = 0; c4 < 4; ++c4) {
      const int c = c4 * 256 + tid;
      f32x4 g = g4[c];
      f32x4 o;
      o.x = omt * g.x + C0 * uu[c4].x + C1 * dd[c4].x;
      o.y = omt * g.y + C0 * uu[c4].y + C1 * dd[c4].y;
      o.z = omt * g.z + C0 * uu[c4].z + C1 * dd[c4].z;
      o.w = omt * g.w + C0 * uu[c4].w + C1 * dd[c4].w;
      __builtin_nontemporal_store(o, &o4[c]);
    }
  }
}

// ---------------- host ----------------

extern "C" void kernel_launch(void* const* d_in, const int* in_sizes, int n_in,
                              void* d_out, int out_size, void* d_ws, size_t ws_size,
                              hipStream_t stream)
{
  const float* adj   = (const float*)d_in[0];
  const float* G     = (const float*)d_in[1];
  const float* feats = (const float*)d_in[2];
  const float* Wl    = (const float*)d_in[3];
  const float* Wv    = (const float*)d_in[4];
  const float* wo_w  = (const float*)d_in[5];
  const float* wo_b  = (const float*)d_in[6];
  const float* g1    = (const float*)d_in[7];
  const float* b1    = (const float*)d_in[8];
  const float* g2    = (const float*)d_in[9];
  const float* b2    = (const float*)d_in[10];
  const int*   num   = (const int*)d_in[11];
  const int*   sigma = (const int*)d_in[12];
  float* out = (float*)d_out;

  hipFuncSetAttribute((const void*)gemm_nt_big8, hipFuncAttributeMaxDynamicSharedMemorySize, 65536);

  char* w = (char*)d_ws;
  auto take = [&](size_t b) { void* p = (void*)w; w += (b + 255) & ~(size_t)255; return p; };
  // zero-region: deg, rsumS, D, SW, sums (contiguous; zeroed by k_zero)
  float* deg   = (float*)take(E_N * 4);
  float* rsumS = (float*)take(V_N * 4);
  float* Dv    = (float*)take(256 * 4);
  float* SWv   = (float*)take(256 * 4);
  float* sums  = (float*)take(256);
  // written-not-accumulated:
  float* aE    = (float*)take(E_N * 4);
  float* cV    = (float*)take(V_N * 4);
  float* DV    = (float*)take(V_N * 4);
  float* uvv   = (float*)take(V_N * 4);
  float* udvv  = (float*)take(V_N * 4);
  float* scal  = (float*)take(256);
  // big0 (20.5 MB): featsb + WcatT + adjTb; later: d_mat8 (8 slices x V x H bf16 = 16 MB)
  char* big0   = (char*)take((size_t)V_N * F_N * 2 + 512 * 512 * 2 + (size_t)E_N * V_N * 2);
  u16* featsb  = (u16*)big0;
  u16* WcatT   = (u16*)(big0 + (size_t)V_N * F_N * 2);
  u16* adjTb   = (u16*)(big0 + (size_t)V_N * F_N * 2 + 512 * 512 * 2);
  u16* d_mat8  = (u16*)big0;
  // big1 (8.4 MB): fwcatb (4 MB) -> s_raw8 (8 slices x E x H bf16 = 8 MB)
  char* big1   = (char*)take((size_t)V_N * 512 * 4 + 256);
  u16* fwcatb  = (u16*)big1;
  u16* s_raw8  = (u16*)big1;
  u16* fwlinT  = (u16*)take((size_t)H_N * V_N * 2);
  u16* fvT     = (u16*)take((size_t)H_N * V_N * 2);
  ull* fvb8    = (ull*)take((size_t)V_N * H_N);
  u16* sw_b    = (u16*)take((size_t)E_N * H_N * 2);
  u16* d_b     = (u16*)take((size_t)V_N * H_N * 2);
  u16* expsb   = (u16*)take((size_t)V_N * V_N * 2);
  (void)in_sizes; (void)n_in; (void)out_size;
  if ((size_t)(w - (char*)d_ws) > ws_size) return;

  // zero the accumulation region with a kernel (avoids the blit-path floor)
  k_zero<<<(NZERO / 4 + 255) / 256, 256, 0, stream>>>(deg);

  // prep: adj transpose+deg, feats->bf16, Wcat transpose (one launch)
  k_prep<<<11264, 256, 0, stream>>>(adj, feats, Wl, Wv, adjTb, deg, featsb, WcatT);

  // G1: fwcatb = bf16(feats @ [W_lin|W_v])   (M=V, N=512, K=512)
  gemm_nt<1><<<dim3(512 / BN, V_N / BM), 256, 0, stream>>>(
      featsb, WcatT, V_N, 512, 512, 1, 0, fwcatb);
  k_splitfw<<<dim3(16, V_N / 32), 256, 0, stream>>>(fwcatb, fwlinT, fvT, fvb8);

  // G2: s_raw8 slices = adj.T @ fwlin   (M=E, N=H, K=V, split-K 8, bf16 slices)
  gemm_nt<2><<<dim3(H_N / BN, E_N / BM, 8), 256, 0, stream>>>(
      adjTb, fwlinT, E_N, H_N, V_N, 8, (size_t)E_N * H_N, s_raw8);

  // G3: expsb = exp(fv @ fv.T / 16)  (fp8 in, bf16 out) + fused row-sums
  gemm_nt_big8<<<dim3(V_N / 256, V_N / 256), 512, 65536, stream>>>(
      (const u8*)fvb8, (const u8*)fvb8, V_N, H_N, 0.0625f,
      expsb, rsumS);

  // G4: P slices = expS @ fv   (M=V, N=H, K=V, split-K 8, bf16 slices)
  gemm_nt<2><<<dim3(H_N / BN, V_N / BM, 8), 256, 0, stream>>>(
      expsb, fvT, V_N, H_N, V_N, 8, (size_t)V_N * H_N, d_mat8);

  // fused dual LayerNorm (E-rows: s-path -> sw_b/aE; V-rows: d-path -> d_b/cV)
  k_ln8dual<<<E_N + V_N, 256, 0, stream>>>(s_raw8, d_mat8, deg, rsumS,
                                           g1, b1, g2, b2, wo_w,
                                           sw_b, d_b, aE, cV);

  // linearized H statistics + closed-form S/theta scalars
  k_hstats<<<26, 256, 0, stream>>>(d_b, sw_b, aE, cV, Dv, SWv, sums);
  k_dvde<<<V_N + 1, 256, 0, stream>>>(d_b, cV, Dv, SWv, sums,
                                      wo_b, sigma, num, DV, uvv, udvv, scal);

  // out = (1-theta)*G + theta*u_i*u_j*(S + t_i + t_j)  (rank-structure G6)
  k_blend<<<V_N / 8, 256, 0, stream>>>(G, DV, uvv, udvv, scal, out);
}

// Round 17
// 131.591 us; speedup vs baseline: 1.0668x; 1.0322x over previous
//
#include <hip/hip_runtime.h>
#include <hip/hip_bf16.h>
#include <math.h>

#define V_N 4096
#define E_N 2048
#define F_N 512
#define H_N 256

typedef unsigned short u16;
typedef unsigned char u8;
typedef unsigned long long ull;
typedef __attribute__((ext_vector_type(8))) short short8;
typedef __attribute__((ext_vector_type(4))) float f32x4;

union S8L2 { short8 s; long l[2]; };

__device__ __forceinline__ float bf2f(u16 u) {
  union { float f; unsigned int q; } x; x.q = ((unsigned int)u) << 16; return x.f;
}
__device__ __forceinline__ u16 f2bf(float f) {
  union { float f; unsigned int q; } x; x.f = f;
  unsigned int q = x.q + 0x7FFFu + ((x.q >> 16) & 1u);
  return (u16)(q >> 16);
}

__device__ __forceinline__ void gload16(const void* g, void* l) {
  __builtin_amdgcn_global_load_lds((const __attribute__((address_space(1))) void*)g,
                                   (__attribute__((address_space(3))) void*)l,
                                   16, 0, 0);
}

__device__ __forceinline__ float theta_of(int n_) {
  float n = (float)n_;
  return 1.f - (1.f - 0.01f) * (cosf(3.14159265358979f * (n - 1.f) / 10.f) + 1.f) * 0.5f;
}

// pack 8 f32 -> 8 fp8 e4m3 (bytes k0..k0+7 ascending)
__device__ __forceinline__ ull pack8_fp8(const float* p) {
  int w0 = __builtin_amdgcn_cvt_pk_fp8_f32(p[0], p[1], 0, false);
  w0 = __builtin_amdgcn_cvt_pk_fp8_f32(p[2], p[3], w0, true);
  int w1 = __builtin_amdgcn_cvt_pk_fp8_f32(p[4], p[5], 0, false);
  w1 = __builtin_amdgcn_cvt_pk_fp8_f32(p[6], p[7], w1, true);
  return (ull)(unsigned int)w0 | ((ull)(unsigned int)w1 << 32);
}

// pi-permuted byte position of an 8-aligned k-chunk within a row
__device__ __forceinline__ int pi8(int k0) {
  return (k0 & ~63) + (((k0 >> 3) & 3) << 4) + (((k0 >> 5) & 1) << 3);
}

// =================== 256x256 8-phase fp8 NT GEMM (T1+T2+T3+T4+T5) ============
// Zero-conflict LDS geometry (proven round 6). See prior rounds.

#define BARX do { asm volatile("" ::: "memory"); __builtin_amdgcn_s_barrier(); \
                  asm volatile("" ::: "memory"); } while (0)

#define LDA_Q8(buf, mh_) do { \
  _Pragma("unroll") \
  for (int m_ = 0; m_ < 4; ++m_) { \
    int L_ = (wr << 6) + m_ * 16 + (lane & 15); \
    int s_ = (((mh_) << 2) | (lane >> 4)) ^ (lane & 7); \
    S8L2 u_; u_.s = *(const short8*)((buf) + L_ * 128 + s_ * 16); \
    a0[m_] = u_.l[0]; a1[m_] = u_.l[1]; \
  } \
} while (0)

#define LDB_Q8(buf, nh_) do { \
  _Pragma("unroll") \
  for (int n_ = 0; n_ < 2; ++n_) { \
    int L_ = (wc << 5) + n_ * 16 + (lane & 15); \
    int s_ = (((nh_) << 2) | (lane >> 4)) ^ (lane & 7); \
    S8L2 u_; u_.s = *(const short8*)((buf) + L_ * 128 + s_ * 16); \
    b0[(nh_) * 2 + n_] = u_.l[0]; b1[(nh_) * 2 + n_] = u_.l[1]; \
  } \
} while (0)

#define MMA_Q8(mh_, nh_) do { \
  __builtin_amdgcn_s_setprio(1); \
  _Pragma("unroll") \
  for (int m_ = 0; m_ < 4; ++m_) { \
    _Pragma("unroll") \
    for (int n_ = 0; n_ < 2; ++n_) { \
      acc[(mh_) * 4 + m_][(nh_) * 2 + n_] = __builtin_amdgcn_mfma_f32_16x16x32_fp8_fp8( \
          a0[m_], b0[(nh_) * 2 + n_], acc[(mh_) * 4 + m_][(nh_) * 2 + n_], 0, 0, 0); \
      acc[(mh_) * 4 + m_][(nh_) * 2 + n_] = __builtin_amdgcn_mfma_f32_16x16x32_fp8_fp8( \
          a1[m_], b1[(nh_) * 2 + n_], acc[(mh_) * 4 + m_][(nh_) * 2 + n_], 0, 0, 0); \
    } } \
  __builtin_amdgcn_s_setprio(0); \
} while (0)

template<int TILE>
__device__ __forceinline__ void stage_half8(const u8* __restrict__ g, int K, int kt,
                                            u8* lds, int tid, int hh) {
  int L  = hh * 64 + (tid >> 3);
  int su = (tid & 7) ^ (L & 7);
  int hr = su >> 2, gc = su & 3;
  int R;
  if constexpr (TILE == 0) R = (L & 63) + ((L >> 6) << 7) + (hr << 6);
  else                     R = (L & 31) + ((L >> 5) << 6) + (hr << 5);
  gload16(g + (size_t)R * K + kt + (gc << 4), lds + hh * 8192 + (tid << 4));
}

// scores-exp: outB = bf16(exp(acc*scale)); row-sum partials -> rsumP[bx][row]
__global__ __launch_bounds__(512, 2)
void gemm_nt_big8(const u8* __restrict__ A, const u8* __restrict__ B,
                  int N, int K, float scale,
                  u16* __restrict__ outB,
                  float* __restrict__ rsumP)
{
  extern __shared__ __align__(16) u8 lds8[];
  u8* As0 = lds8;
  u8* Bs0 = lds8 + 16384;
  u8* As1 = lds8 + 32768;
  u8* Bs1 = lds8 + 49152;

  const int tid = threadIdx.x, lane = tid & 63, wave = tid >> 6;
  const int wr = wave >> 2, wc = wave & 3;

  const int nwg = gridDim.x * gridDim.y;
  const int lin = blockIdx.y * gridDim.x + blockIdx.x;
  const int swz = (lin & 7) * (nwg >> 3) + (lin >> 3);
  const int bx = swz % gridDim.x, by = swz / gridDim.x;
  const int tileM = by * 256, tileN = bx * 256;

  const u8* Ag = A + (size_t)tileM * K;
  const u8* Bg = B + (size_t)tileN * K;
  const int NT = K / 64;

  f32x4 acc[8][4] = {};
  long a0[4], a1[4], b0[8], b1[8];

  stage_half8<0>(Ag, K, 0, As0, tid, 0);
  stage_half8<0>(Ag, K, 0, As0, tid, 1);
  stage_half8<1>(Bg, K, 0, Bs0, tid, 0);
  stage_half8<1>(Bg, K, 0, Bs0, tid, 1);
  stage_half8<0>(Ag, K, 64, As1, tid, 0);
  stage_half8<1>(Bg, K, 64, Bs1, tid, 0);
  asm volatile("s_waitcnt vmcnt(2)" ::: "memory");
  BARX;

  for (int it = 0; it < NT / 2; ++it) {
    const int t = it * 2;
    const int k1 = (t + 1) * 64, k2 = (t + 2) * 64, k3 = (t + 3) * 64;
    const bool h2 = (t + 2) < NT;
    LDA_Q8(As0, 0); LDB_Q8(Bs0, 0);
    stage_half8<0>(Ag, K, k1, As1, tid, 1);
    BARX; MMA_Q8(0, 0); BARX;

    LDB_Q8(Bs0, 1);
    stage_half8<1>(Bg, K, k1, Bs1, tid, 1);
    BARX; MMA_Q8(0, 1); BARX;

    LDA_Q8(As0, 1);
    if (h2) stage_half8<0>(Ag, K, k2, As0, tid, 0);
    BARX; MMA_Q8(1, 0); BARX;

    if (h2) {
      stage_half8<1>(Bg, K, k2, Bs0, tid, 0);
      asm volatile("s_waitcnt vmcnt(2)" ::: "memory");
    } else {
      asm volatile("s_waitcnt vmcnt(0)" ::: "memory");
    }
    BARX; MMA_Q8(1, 1); BARX;

    LDA_Q8(As1, 0); LDB_Q8(Bs1, 0);
    if (h2) stage_half8<0>(Ag, K, k2, As0, tid, 1);
    BARX; MMA_Q8(0, 0); BARX;

    LDB_Q8(Bs1, 1);
    if (h2) stage_half8<1>(Bg, K, k2, Bs0, tid, 1);
    BARX; MMA_Q8(0, 1); BARX;

    LDA_Q8(As1, 1);
    if (h2) stage_half8<0>(Ag, K, k3, As1, tid, 0);
    BARX; MMA_Q8(1, 0); BARX;

    if (h2) {
      stage_half8<1>(Bg, K, k3, Bs1, tid, 0);
      asm volatile("s_waitcnt vmcnt(2)" ::: "memory");
    } else {
      asm volatile("s_waitcnt vmcnt(0)" ::: "memory");
    }
    BARX; MMA_Q8(1, 1); BARX;
  }

  const int r0 = tileM + wr * 128 + ((lane >> 4) << 2);
  const int c0 = tileN + wc * 64 + (lane & 15);
#pragma unroll
  for (int m = 0; m < 8; ++m) {
#pragma unroll
    for (int j = 0; j < 4; ++j) {
      const int row = r0 + m * 16 + j;
      float rsum = 0.f;
#pragma unroll
      for (int n = 0; n < 4; ++n) {
        const int col = c0 + n * 16;
        float hv = __expf(acc[m][n][j] * scale);
        outB[(size_t)row * N + col] = f2bf(hv);
        rsum += hv;
      }
      rsum += __shfl_xor(rsum, 1); rsum += __shfl_xor(rsum, 2);
      rsum += __shfl_xor(rsum, 4); rsum += __shfl_xor(rsum, 8);
      if ((lane & 15) == 0) rsumP[(size_t)bx * N + row] = rsum;  // disjoint slice
    }
  }
}

// =================== 128x128 bf16 MFMA NT GEMM (skinny shapes) ===============
// XOR-swizzled LDS. EPI 1 = full bf16 store; EPI 2 = bf16 SLICE store.
#define BM 128
#define BN 128
#define BK 64

template<int EPI>
__global__ __launch_bounds__(256)
void gemm_nt(const u16* __restrict__ A, const u16* __restrict__ B,
             int M, int N, int K, int ksplit, size_t sstride,
             u16* __restrict__ outB)
{
  __shared__ __align__(16) u16 As[BM * BK];
  __shared__ __align__(16) u16 Bs[BN * BK];
  const int tid  = threadIdx.x;
  const int lane = tid & 63;
  const int wave = tid >> 6;
  const int wr = wave >> 1, wc = wave & 1;

  int bxx = blockIdx.x, byy = blockIdx.y, bzz = blockIdx.z;
  if (gridDim.x == 2) {
    int lin = bxx + 2 * (byy + gridDim.y * bzz);
    bxx = (lin >> 3) & 1;
    int q = (lin & 7) | ((lin >> 4) << 3);
    byy = q % gridDim.y;
    bzz = q / gridDim.y;
  }
  const int tileM = byy * BM;
  const int tileN = bxx * BN;
  const int kper = K / ksplit;
  const int kbeg = bzz * kper;
  const int kend = kbeg + kper;

  const int srow = wave * 8 + (lane >> 3);
  const int sdst = (lane & 7) * 8;
  const int ssrc = ((lane & 7) ^ (lane >> 3)) * 8;

  f32x4 acc[4][4] = {};

  const u16* Arow = A + (size_t)tileM * K;
  const u16* Brow = B + (size_t)tileN * K;

  for (int kt = kbeg; kt < kend; kt += BK) {
    __syncthreads();
#pragma unroll
    for (int r = 0; r < 4; ++r) {
      int row = r * 32 + srow;
      gload16(Arow + (size_t)row * K + kt + ssrc, &As[row * BK + sdst]);
      gload16(Brow + (size_t)row * K + kt + ssrc, &Bs[row * BK + sdst]);
    }
    __syncthreads();
#pragma unroll
    for (int ks = 0; ks < 2; ++ks) {
      short8 af[4], bfq[4];
#pragma unroll
      for (int m = 0; m < 4; ++m)
        af[m] = *(const short8*)&As[(wr * 64 + m * 16 + (lane & 15)) * BK
                 + ((((ks << 2) | (lane >> 4)) ^ (lane & 7)) << 3)];
#pragma unroll
      for (int n = 0; n < 4; ++n)
        bfq[n] = *(const short8*)&Bs[(wc * 64 + n * 16 + (lane & 15)) * BK
                 + ((((ks << 2) | (lane >> 4)) ^ (lane & 7)) << 3)];
#pragma unroll
      for (int m = 0; m < 4; ++m)
#pragma unroll
        for (int n = 0; n < 4; ++n)
          acc[m][n] = __builtin_amdgcn_mfma_f32_16x16x32_bf16(af[m], bfq[n], acc[m][n], 0, 0, 0);
    }
  }

  const int r0 = tileM + wr * 64 + ((lane >> 4) << 2);
  const int c0 = tileN + wc * 64 + (lane & 15);
  u16* oB = (EPI == 2) ? (outB + (size_t)bzz * sstride) : outB;
#pragma unroll
  for (int m = 0; m < 4; ++m) {
#pragma unroll
    for (int j = 0; j < 4; ++j) {
      const int row = r0 + m * 16 + j;
#pragma unroll
      for (int n = 0; n < 4; ++n) {
        const int col = c0 + n * 16;
        oB[(size_t)row * N + col] = f2bf(acc[m][n][j]);
      }
    }
  }
}

// ---------------- utility kernels ----------------

// merged prep: blocks 0..8191 = adj transpose + degree PARTIALS (no atomics);
// 8192..10239 = feats->bf16; 10240..11263 = Wcat transpose->bf16;
// 11264 = zero Dv/SWv/sums (consumed by k_hstats much later)
__global__ void k_prep(const float* __restrict__ adj, const float* __restrict__ feats,
                       const float* __restrict__ Wl, const float* __restrict__ Wv,
                       u16* __restrict__ adjT, float* __restrict__ degP,
                       u16* __restrict__ featsb, u16* __restrict__ WT,
                       float* __restrict__ zreg) {
  __shared__ float t[32][33];
  int bx = blockIdx.x;
  if (bx < 8192) {
    int e0 = (bx & 63) * 32, v0 = (bx >> 6) * 32;
    int tx = threadIdx.x & 31, ty = threadIdx.x >> 5;
    for (int i = ty; i < 32; i += 8)
      t[i][tx] = adj[(size_t)(v0 + i) * E_N + e0 + tx];
    __syncthreads();
    for (int i = ty; i < 32; i += 8)
      adjT[(size_t)(e0 + i) * V_N + v0 + tx] = f2bf(t[tx][i]);
    if (ty == 0) {
      float s = 0.f;
#pragma unroll
      for (int i = 0; i < 32; ++i) s += t[i][tx];
      degP[(size_t)(v0 >> 5) * E_N + e0 + tx] = s;   // disjoint partial
    }
  } else if (bx < 10240) {
    int i = (bx - 8192) * 256 + threadIdx.x;
    float4 v = ((const float4*)feats)[i];
    ushort4 o; o.x = f2bf(v.x); o.y = f2bf(v.y); o.z = f2bf(v.z); o.w = f2bf(v.w);
    ((ushort4*)featsb)[i] = o;
  } else if (bx < 11264) {
    int id = (bx - 10240) * 256 + threadIdx.x;
    int n = id >> 9, k = id & 511;
    float v = (n < 256) ? Wl[(size_t)k * 256 + n] : Wv[(size_t)k * 256 + (n - 256)];
    WT[id] = f2bf(v);
  } else {
    // zero Dv(256) + SWv(256) + sums(64) = 576 floats, laid out contiguously
    if (threadIdx.x < 144) ((f32x4*)zreg)[threadIdx.x] = (f32x4){0.f, 0.f, 0.f, 0.f};
  }
}

// fwcatb (V,512) bf16 -> fwlinT (256,V), fvT (256,V) + fused fp8-pi pack of fv
__global__ void k_splitfw(const u16* __restrict__ fw, u16* __restrict__ fwlinT,
                          u16* __restrict__ fvT, ull* __restrict__ fvb8) {
  __shared__ u16 t[32][33];
  int h0 = blockIdx.x * 32, v0 = blockIdx.y * 32;
  int tx = threadIdx.x & 31, ty = threadIdx.x >> 5;
  for (int i = ty; i < 32; i += 8)
    t[i][tx] = fw[(size_t)(v0 + i) * 512 + h0 + tx];
  __syncthreads();
  u16* oT = (h0 < 256) ? fwlinT : fvT;
  int hb = (h0 < 256) ? h0 : h0 - 256;
  for (int i = ty; i < 32; i += 8)
    oT[(size_t)(hb + i) * V_N + v0 + tx] = t[tx][i];
  if (h0 >= 256 && threadIdx.x < 128) {
    int i = threadIdx.x >> 2, c = threadIdx.x & 3;
    int k0 = (h0 - 256) + c * 8;
    float f[8];
#pragma unroll
    for (int j = 0; j < 8; ++j) f[j] = bf2f(t[i][c * 8 + j]);
    fvb8[(size_t)(v0 + i) * 32 + (pi8(k0) >> 3)] = pack8_fp8(f);
  }
}

// Fused dual LayerNorm over bf16 slice sums (8 slices each path).
// Divisor from partials: E-path = sum of 128 degP slices; V-path = 16 rsumP.
__global__ void k_ln8dual(const u16* __restrict__ XE8, const u16* __restrict__ XV8,
                          const float* __restrict__ degP, const float* __restrict__ rsumP,
                          const float* __restrict__ g1, const float* __restrict__ b1,
                          const float* __restrict__ g2, const float* __restrict__ b2,
                          const float* __restrict__ w,
                          u16* __restrict__ sw_b, u16* __restrict__ d_b,
                          float* __restrict__ aE, float* __restrict__ cV)
{
  __shared__ float sm[8];
  __shared__ float dsm[2];
  const int bid = blockIdx.x, tid = threadIdx.x, lane = tid & 63, wave = tid >> 6;
  const bool isE = bid < E_N;
  const int row = isE ? bid : bid - E_N;
  const u16* X = isE ? XE8 : XV8;
  const size_t sstr = isE ? (size_t)E_N * H_N : (size_t)V_N * H_N;
  const float* gg = isE ? g1 : g2;
  const float* bb = isE ? b1 : b2;
  u16* outB = isE ? sw_b : d_b;
  float* outA = isE ? aE : cV;

  // divisor reduction from partials
  const float* Pp = isE ? degP : rsumP;
  const int nP = isE ? 128 : 16;
  const int pstr = isE ? E_N : V_N;
  float pv = (tid < nP) ? Pp[(size_t)tid * pstr + row] : 0.f;
#pragma unroll
  for (int o = 32; o > 0; o >>= 1) pv += __shfl_down(pv, o);
  if (wave < 2 && lane == 0) dsm[wave] = pv;

  float x = 0.f;
#pragma unroll
  for (int s = 0; s < 8; ++s)
    x += bf2f(X[(size_t)s * sstr + (size_t)row * 256 + tid]);
  __syncthreads();
  x /= (dsm[0] + dsm[1]);
  float s1 = x, s2 = x * x;
#pragma unroll
  for (int o = 32; o > 0; o >>= 1) { s1 += __shfl_down(s1, o); s2 += __shfl_down(s2, o); }
  if (lane == 0) { sm[wave] = s1; sm[4 + wave] = s2; }
  __syncthreads();
  float sx  = sm[0] + sm[1] + sm[2] + sm[3];
  float sx2 = sm[4] + sm[5] + sm[6] + sm[7];
  float mu  = sx * (1.f / 256.f);
  float var = sx2 * (1.f / 256.f) - mu * mu;
  float rs  = rsqrtf(var + 1e-5f);
  float xln = (x - mu) * rs * gg[tid] + bb[tid];
  outB[(size_t)row * 256 + tid] = f2bf(isE ? xln * w[tid] : xln);
  float t = w[tid] * xln * xln;
  __syncthreads();
#pragma unroll
  for (int o = 32; o > 0; o >>= 1) t += __shfl_down(t, o);
  if (lane == 0) sm[wave] = t;
  __syncthreads();
  if (tid == 0) outA[row] = sm[0] + sm[1] + sm[2] + sm[3];
}

// H-stats, stage 1: D[h] = sum_v d[v][h], SW[h] = sum_e sw[e][h],
// sums[0] = sum aE, sums[1] = sum cV. (targets zeroed by k_prep)
__global__ void k_hstats(const u16* __restrict__ d_b, const u16* __restrict__ sw_b,
                         const float* __restrict__ aE, const float* __restrict__ cV,
                         float* __restrict__ D, float* __restrict__ SW,
                         float* __restrict__ sums) {
  int b = blockIdx.x, tid = threadIdx.x;
  if (b < 16) {
    float acc = 0.f;
    const u16* p = d_b + (size_t)b * 256 * 256 + tid;
    for (int r = 0; r < 256; ++r) acc += bf2f(p[r * 256]);
    atomicAdd(&D[tid], acc);
  } else if (b < 24) {
    float acc = 0.f;
    const u16* p = sw_b + (size_t)(b - 16) * 256 * 256 + tid;
    for (int r = 0; r < 256; ++r) acc += bf2f(p[r * 256]);
    atomicAdd(&SW[tid], acc);
  } else {
    const float* src = (b == 24) ? aE : cV;
    const int n = (b == 24) ? E_N : V_N;
    float s = 0.f;
    for (int i = tid; i < n; i += 256) s += src[i];
#pragma unroll
    for (int o = 32; o > 0; o >>= 1) s += __shfl_down(s, o);
    if ((tid & 63) == 0) atomicAdd(&sums[b - 24], s);
  }
}

// H-stats, stage 2 (linearized H): blocks 0..V-1: DV/uv/udv per row.
// Block V: closed-form S and scal[] for k_blend.
__global__ void k_dvde(const u16* __restrict__ d_b,
                       const float* __restrict__ cV,
                       const float* __restrict__ D, const float* __restrict__ SW,
                       const float* __restrict__ sums, const float* __restrict__ biasp,
                       const int* __restrict__ sigmap, const int* __restrict__ num,
                       float* __restrict__ DV,
                       float* __restrict__ uv, float* __restrict__ udv,
                       float* __restrict__ scal) {
  __shared__ float sm[4];
  const int b = blockIdx.x, tid = threadIdx.x, lane = tid & 63, wave = tid >> 6;
  float x;
  if (b < V_N) {
    x = bf2f(d_b[(size_t)b * 256 + tid]) * SW[tid];
  } else {
    x = SW[tid] * D[tid];
  }
#pragma unroll
  for (int o = 32; o > 0; o >>= 1) x += __shfl_down(x, o);
  if (lane == 0) sm[wave] = x;
  __syncthreads();
  if (tid == 0) {
    const float dot = sm[0] + sm[1] + sm[2] + sm[3];
    const float sgm = (float)sigmap[0];
    const float i2s = 1.f / (2.f * sgm * sgm);
    const float bias = biasp[0];
    if (b < V_N) {
      float dv = (float)E_N - i2s * (sums[0] + (float)E_N * (cV[b] + bias) - 2.f * dot);
      DV[b] = dv;
      float u = rsqrtf(dv);
      uv[b] = u;
      udv[b] = u * dv;            // = sqrt(dv)
    } else {
      const float T = (float)V_N * (sums[0] + (float)E_N * bias)
                    + (float)E_N * sums[1] - 2.f * dot;
      const float S = (float)E_N / (float)V_N
                    + i2s * T / ((float)V_N * (float)V_N);
      const float theta = theta_of(num[0]);
      scal[0] = 1.f - theta;
      scal[1] = theta * S * (1.f / (float)E_N);
    }
  }
}

// out[i,j] = scal0*G + C0*uv[j] + C1*udv[j];  C1 = scal1*uv_i, C0 = C1*(DV_i-E).
// NONTEMPORAL loads on G (bypass the slow L3-hit path: round-16 FETCH=33MB
// showed half of G L3-served at only ~0.8 TB/s) + nt stores. 8 rows/block.
__global__ __launch_bounds__(256)
void k_blend(const float* __restrict__ G, const float* __restrict__ DV,
             const float* __restrict__ uv, const float* __restrict__ udv,
             const float* __restrict__ scal, float* __restrict__ out) {
  const int tid = threadIdx.x;
  const float omt = scal[0], tk = scal[1];
  const int row0 = blockIdx.x * 8;

  f32x4 uu[4], dd[4];
  const f32x4* u4 = (const f32x4*)uv;
  const f32x4* ud4 = (const f32x4*)udv;
#pragma unroll
  for (int c4 = 0; c4 < 4; ++c4) {
    uu[c4] = u4[c4 * 256 + tid];
    dd[c4] = ud4[c4 * 256 + tid];
  }

#pragma unroll
  for (int rr = 0; rr < 8; ++rr) {
    const int row = row0 + rr;
    const float uvi = uv[row];
    const float C1 = tk * uvi;
    const float C0 = C1 * (DV[row] - (float)E_N);
    const f32x4* g4 = (const f32x4*)(G + (size_t)row * V_N);
    f32x4* o4 = (f32x4*)(out + (size_t)row * V_N);
#pragma unroll
    for (int c4 = 0; c4 < 4; ++c4) {
      const int c = c4 * 256 + tid;
      f32x4 g = __builtin_nontemporal_load(&g4[c]);
      f32x4 o;
      o.x = omt * g.x + C0 * uu[c4].x + C1 * dd[c4].x;
      o.y = omt * g.y + C0 * uu[c4].y + C1 * dd[c4].y;
      o.z = omt * g.z + C0 * uu[c4].z + C1 * dd[c4].z;
      o.w = omt * g.w + C0 * uu[c4].w + C1 * dd[c4].w;
      __builtin_nontemporal_store(o, &o4[c]);
    }
  }
}

// ---------------- host ----------------

extern "C" void kernel_launch(void* const* d_in, const int* in_sizes, int n_in,
                              void* d_out, int out_size, void* d_ws, size_t ws_size,
                              hipStream_t stream)
{
  const float* adj   = (const float*)d_in[0];
  const float* G     = (const float*)d_in[1];
  const float* feats = (const float*)d_in[2];
  const float* Wl    = (const float*)d_in[3];
  const float* Wv    = (const float*)d_in[4];
  const float* wo_w  = (const float*)d_in[5];
  const float* wo_b  = (const float*)d_in[6];
  const float* g1    = (const float*)d_in[7];
  const float* b1    = (const float*)d_in[8];
  const float* g2    = (const float*)d_in[9];
  const float* b2    = (const float*)d_in[10];
  const int*   num   = (const int*)d_in[11];
  const int*   sigma = (const int*)d_in[12];
  float* out = (float*)d_out;

  hipFuncSetAttribute((const void*)gemm_nt_big8, hipFuncAttributeMaxDynamicSharedMemorySize, 65536);

  char* w = (char*)d_ws;
  auto take = [&](size_t b) { void* p = (void*)w; w += (b + 255) & ~(size_t)255; return p; };
  // zero-region (zeroed by k_prep block 11264): Dv, SWv, sums (contiguous)
  float* Dv    = (float*)take(256 * 4);
  float* SWv   = (float*)take(256 * 4);
  float* sums  = (float*)take(256);
  // partial-sum buffers (every slot written before read - no zeroing):
  float* degP  = (float*)take((size_t)128 * E_N * 4);   // 1 MB
  float* rsumP = (float*)take((size_t)16 * V_N * 4);    // 256 KB
  // written-not-accumulated:
  float* aE    = (float*)take(E_N * 4);
  float* cV    = (float*)take(V_N * 4);
  float* DV    = (float*)take(V_N * 4);
  float* uvv   = (float*)take(V_N * 4);
  float* udvv  = (float*)take(V_N * 4);
  float* scal  = (float*)take(256);
  // big0 (20.5 MB): featsb + WcatT + adjTb; later: d_mat8 (8 slices x V x H bf16)
  char* big0   = (char*)take((size_t)V_N * F_N * 2 + 512 * 512 * 2 + (size_t)E_N * V_N * 2);
  u16* featsb  = (u16*)big0;
  u16* WcatT   = (u16*)(big0 + (size_t)V_N * F_N * 2);
  u16* adjTb   = (u16*)(big0 + (size_t)V_N * F_N * 2 + 512 * 512 * 2);
  u16* d_mat8  = (u16*)big0;
  // big1 (8.4 MB): fwcatb (4 MB) -> s_raw8 (8 slices x E x H bf16 = 8 MB)
  char* big1   = (char*)take((size_t)V_N * 512 * 4 + 256);
  u16* fwcatb  = (u16*)big1;
  u16* s_raw8  = (u16*)big1;
  u16* fwlinT  = (u16*)take((size_t)H_N * V_N * 2);
  u16* fvT     = (u16*)take((size_t)H_N * V_N * 2);
  ull* fvb8    = (ull*)take((size_t)V_N * H_N);
  u16* sw_b    = (u16*)take((size_t)E_N * H_N * 2);
  u16* d_b     = (u16*)take((size_t)V_N * H_N * 2);
  u16* expsb   = (u16*)take((size_t)V_N * V_N * 2);
  (void)in_sizes; (void)n_in; (void)out_size;
  if ((size_t)(w - (char*)d_ws) > ws_size) return;

  // prep: adj transpose + degree partials, feats->bf16, Wcat transpose,
  // zero Dv/SWv/sums (one launch, no memset, no atomics)
  k_prep<<<11265, 256, 0, stream>>>(adj, feats, Wl, Wv, adjTb, degP, featsb, WcatT, Dv);

  // G1: fwcatb = bf16(feats @ [W_lin|W_v])   (M=V, N=512, K=512)
  gemm_nt<1><<<dim3(512 / BN, V_N / BM), 256, 0, stream>>>(
      featsb, WcatT, V_N, 512, 512, 1, 0, fwcatb);
  k_splitfw<<<dim3(16, V_N / 32), 256, 0, stream>>>(fwcatb, fwlinT, fvT, fvb8);

  // G2: s_raw8 slices = adj.T @ fwlin   (M=E, N=H, K=V, split-K 8, bf16 slices)
  gemm_nt<2><<<dim3(H_N / BN, E_N / BM, 8), 256, 0, stream>>>(
      adjTb, fwlinT, E_N, H_N, V_N, 8, (size_t)E_N * H_N, s_raw8);

  // G3: expsb = exp(fv @ fv.T / 16)  (fp8 in, bf16 out) + row-sum partials
  gemm_nt_big8<<<dim3(V_N / 256, V_N / 256), 512, 65536, stream>>>(
      (const u8*)fvb8, (const u8*)fvb8, V_N, H_N, 0.0625f,
      expsb, rsumP);

  // G4: P slices = expS @ fv   (M=V, N=H, K=V, split-K 8, bf16 slices)
  gemm_nt<2><<<dim3(H_N / BN, V_N / BM, 8), 256, 0, stream>>>(
      expsb, fvT, V_N, H_N, V_N, 8, (size_t)V_N * H_N, d_mat8);

  // fused dual LayerNorm (divisors reduced from degP / rsumP partials)
  k_ln8dual<<<E_N + V_N, 256, 0, stream>>>(s_raw8, d_mat8, degP, rsumP,
                                           g1, b1, g2, b2, wo_w,
                                           sw_b, d_b, aE, cV);

  // linearized H statistics + closed-form S/theta scalars
  k_hstats<<<26, 256, 0, stream>>>(d_b, sw_b, aE, cV, Dv, SWv, sums);
  k_dvde<<<V_N + 1, 256, 0, stream>>>(d_b, cV, Dv, SWv, sums,
                                      wo_b, sigma, num, DV, uvv, udvv, scal);

  // out = (1-theta)*G + theta*u_i*u_j*(S + t_i + t_j)  (rank-structure G6)
  k_blend<<<V_N / 8, 256, 0, stream>>>(G, DV, uvv, udvv, scal, out);
}

// Round 18
// 131.117 us; speedup vs baseline: 1.0707x; 1.0036x over previous
//
#include <hip/hip_runtime.h>
#include <hip/hip_bf16.h>
#include <math.h>

#define V_N 4096
#define E_N 2048
#define F_N 512
#define H_N 256

typedef unsigned short u16;
typedef unsigned char u8;
typedef unsigned long long ull;
typedef __attribute__((ext_vector_type(8))) short short8;
typedef __attribute__((ext_vector_type(4))) float f32x4;

union S8L2 { short8 s; long l[2]; };

__device__ __forceinline__ float bf2f(u16 u) {
  union { float f; unsigned int q; } x; x.q = ((unsigned int)u) << 16; return x.f;
}
__device__ __forceinline__ u16 f2bf(float f) {
  union { float f; unsigned int q; } x; x.f = f;
  unsigned int q = x.q + 0x7FFFu + ((x.q >> 16) & 1u);
  return (u16)(q >> 16);
}

__device__ __forceinline__ void gload16(const void* g, void* l) {
  __builtin_amdgcn_global_load_lds((const __attribute__((address_space(1))) void*)g,
                                   (__attribute__((address_space(3))) void*)l,
                                   16, 0, 0);
}

__device__ __forceinline__ float theta_of(int n_) {
  float n = (float)n_;
  return 1.f - (1.f - 0.01f) * (cosf(3.14159265358979f * (n - 1.f) / 10.f) + 1.f) * 0.5f;
}

// pack 8 f32 -> 8 fp8 e4m3 (bytes k0..k0+7 ascending)
__device__ __forceinline__ ull pack8_fp8(const float* p) {
  int w0 = __builtin_amdgcn_cvt_pk_fp8_f32(p[0], p[1], 0, false);
  w0 = __builtin_amdgcn_cvt_pk_fp8_f32(p[2], p[3], w0, true);
  int w1 = __builtin_amdgcn_cvt_pk_fp8_f32(p[4], p[5], 0, false);
  w1 = __builtin_amdgcn_cvt_pk_fp8_f32(p[6], p[7], w1, true);
  return (ull)(unsigned int)w0 | ((ull)(unsigned int)w1 << 32);
}

// pi-permuted byte position of an 8-aligned k-chunk within a row
__device__ __forceinline__ int pi8(int k0) {
  return (k0 & ~63) + (((k0 >> 3) & 3) << 4) + (((k0 >> 5) & 1) << 3);
}

// =================== 256x256 8-phase fp8 NT GEMM (T1+T2+T3+T4+T5) ============
// Zero-conflict LDS geometry (proven round 6). See prior rounds.

#define BARX do { asm volatile("" ::: "memory"); __builtin_amdgcn_s_barrier(); \
                  asm volatile("" ::: "memory"); } while (0)

#define LDA_Q8(buf, mh_) do { \
  _Pragma("unroll") \
  for (int m_ = 0; m_ < 4; ++m_) { \
    int L_ = (wr << 6) + m_ * 16 + (lane & 15); \
    int s_ = (((mh_) << 2) | (lane >> 4)) ^ (lane & 7); \
    S8L2 u_; u_.s = *(const short8*)((buf) + L_ * 128 + s_ * 16); \
    a0[m_] = u_.l[0]; a1[m_] = u_.l[1]; \
  } \
} while (0)

#define LDB_Q8(buf, nh_) do { \
  _Pragma("unroll") \
  for (int n_ = 0; n_ < 2; ++n_) { \
    int L_ = (wc << 5) + n_ * 16 + (lane & 15); \
    int s_ = (((nh_) << 2) | (lane >> 4)) ^ (lane & 7); \
    S8L2 u_; u_.s = *(const short8*)((buf) + L_ * 128 + s_ * 16); \
    b0[(nh_) * 2 + n_] = u_.l[0]; b1[(nh_) * 2 + n_] = u_.l[1]; \
  } \
} while (0)

#define MMA_Q8(mh_, nh_) do { \
  __builtin_amdgcn_s_setprio(1); \
  _Pragma("unroll") \
  for (int m_ = 0; m_ < 4; ++m_) { \
    _Pragma("unroll") \
    for (int n_ = 0; n_ < 2; ++n_) { \
      acc[(mh_) * 4 + m_][(nh_) * 2 + n_] = __builtin_amdgcn_mfma_f32_16x16x32_fp8_fp8( \
          a0[m_], b0[(nh_) * 2 + n_], acc[(mh_) * 4 + m_][(nh_) * 2 + n_], 0, 0, 0); \
      acc[(mh_) * 4 + m_][(nh_) * 2 + n_] = __builtin_amdgcn_mfma_f32_16x16x32_fp8_fp8( \
          a1[m_], b1[(nh_) * 2 + n_], acc[(mh_) * 4 + m_][(nh_) * 2 + n_], 0, 0, 0); \
    } } \
  __builtin_amdgcn_s_setprio(0); \
} while (0)

template<int TILE>
__device__ __forceinline__ void stage_half8(const u8* __restrict__ g, int K, int kt,
                                            u8* lds, int tid, int hh) {
  int L  = hh * 64 + (tid >> 3);
  int su = (tid & 7) ^ (L & 7);
  int hr = su >> 2, gc = su & 3;
  int R;
  if constexpr (TILE == 0) R = (L & 63) + ((L >> 6) << 7) + (hr << 6);
  else                     R = (L & 31) + ((L >> 5) << 6) + (hr << 5);
  gload16(g + (size_t)R * K + kt + (gc << 4), lds + hh * 8192 + (tid << 4));
}

// scores-exp: outB = bf16(exp(acc*scale)); row-sum partials -> rsumP[bx][row]
__global__ __launch_bounds__(512, 2)
void gemm_nt_big8(const u8* __restrict__ A, const u8* __restrict__ B,
                  int N, int K, float scale,
                  u16* __restrict__ outB,
                  float* __restrict__ rsumP)
{
  extern __shared__ __align__(16) u8 lds8[];
  u8* As0 = lds8;
  u8* Bs0 = lds8 + 16384;
  u8* As1 = lds8 + 32768;
  u8* Bs1 = lds8 + 49152;

  const int tid = threadIdx.x, lane = tid & 63, wave = tid >> 6;
  const int wr = wave >> 2, wc = wave & 3;

  const int nwg = gridDim.x * gridDim.y;
  const int lin = blockIdx.y * gridDim.x + blockIdx.x;
  const int swz = (lin & 7) * (nwg >> 3) + (lin >> 3);
  const int bx = swz % gridDim.x, by = swz / gridDim.x;
  const int tileM = by * 256, tileN = bx * 256;

  const u8* Ag = A + (size_t)tileM * K;
  const u8* Bg = B + (size_t)tileN * K;
  const int NT = K / 64;

  f32x4 acc[8][4] = {};
  long a0[4], a1[4], b0[8], b1[8];

  stage_half8<0>(Ag, K, 0, As0, tid, 0);
  stage_half8<0>(Ag, K, 0, As0, tid, 1);
  stage_half8<1>(Bg, K, 0, Bs0, tid, 0);
  stage_half8<1>(Bg, K, 0, Bs0, tid, 1);
  stage_half8<0>(Ag, K, 64, As1, tid, 0);
  stage_half8<1>(Bg, K, 64, Bs1, tid, 0);
  asm volatile("s_waitcnt vmcnt(2)" ::: "memory");
  BARX;

  for (int it = 0; it < NT / 2; ++it) {
    const int t = it * 2;
    const int k1 = (t + 1) * 64, k2 = (t + 2) * 64, k3 = (t + 3) * 64;
    const bool h2 = (t + 2) < NT;
    LDA_Q8(As0, 0); LDB_Q8(Bs0, 0);
    stage_half8<0>(Ag, K, k1, As1, tid, 1);
    BARX; MMA_Q8(0, 0); BARX;

    LDB_Q8(Bs0, 1);
    stage_half8<1>(Bg, K, k1, Bs1, tid, 1);
    BARX; MMA_Q8(0, 1); BARX;

    LDA_Q8(As0, 1);
    if (h2) stage_half8<0>(Ag, K, k2, As0, tid, 0);
    BARX; MMA_Q8(1, 0); BARX;

    if (h2) {
      stage_half8<1>(Bg, K, k2, Bs0, tid, 0);
      asm volatile("s_waitcnt vmcnt(2)" ::: "memory");
    } else {
      asm volatile("s_waitcnt vmcnt(0)" ::: "memory");
    }
    BARX; MMA_Q8(1, 1); BARX;

    LDA_Q8(As1, 0); LDB_Q8(Bs1, 0);
    if (h2) stage_half8<0>(Ag, K, k2, As0, tid, 1);
    BARX; MMA_Q8(0, 0); BARX;

    LDB_Q8(Bs1, 1);
    if (h2) stage_half8<1>(Bg, K, k2, Bs0, tid, 1);
    BARX; MMA_Q8(0, 1); BARX;

    LDA_Q8(As1, 1);
    if (h2) stage_half8<0>(Ag, K, k3, As1, tid, 0);
    BARX; MMA_Q8(1, 0); BARX;

    if (h2) {
      stage_half8<1>(Bg, K, k3, Bs1, tid, 0);
      asm volatile("s_waitcnt vmcnt(2)" ::: "memory");
    } else {
      asm volatile("s_waitcnt vmcnt(0)" ::: "memory");
    }
    BARX; MMA_Q8(1, 1); BARX;
  }

  const int r0 = tileM + wr * 128 + ((lane >> 4) << 2);
  const int c0 = tileN + wc * 64 + (lane & 15);
#pragma unroll
  for (int m = 0; m < 8; ++m) {
#pragma unroll
    for (int j = 0; j < 4; ++j) {
      const int row = r0 + m * 16 + j;
      float rsum = 0.f;
#pragma unroll
      for (int n = 0; n < 4; ++n) {
        const int col = c0 + n * 16;
        float hv = __expf(acc[m][n][j] * scale);
        outB[(size_t)row * N + col] = f2bf(hv);
        rsum += hv;
      }
      rsum += __shfl_xor(rsum, 1); rsum += __shfl_xor(rsum, 2);
      rsum += __shfl_xor(rsum, 4); rsum += __shfl_xor(rsum, 8);
      if ((lane & 15) == 0) rsumP[(size_t)bx * N + row] = rsum;  // disjoint slice
    }
  }
}

// =================== 128x128 bf16 MFMA NT GEMM (skinny shapes) ===============
// XOR-swizzled LDS. EPI 1 = full bf16 store; EPI 2 = bf16 SLICE store;
// EPI 3 = G1 fused epilogue: LDS transpose -> fwlinT/fvT + fp8-pi pack of fv.
#define BM 128
#define BN 128
#define BK 64

template<int EPI>
__global__ __launch_bounds__(256)
void gemm_nt(const u16* __restrict__ A, const u16* __restrict__ B,
             int M, int N, int K, int ksplit, size_t sstride,
             u16* __restrict__ outB,
             u16* __restrict__ fwlinT, u16* __restrict__ fvT,
             ull* __restrict__ fvb8)
{
  __shared__ __align__(16) u16 sh[BM * BK * 2];
  u16* As = sh;
  u16* Bs = sh + BM * BK;
  const int tid  = threadIdx.x;
  const int lane = tid & 63;
  const int wave = tid >> 6;
  const int wr = wave >> 1, wc = wave & 1;

  int bxx = blockIdx.x, byy = blockIdx.y, bzz = blockIdx.z;
  if (gridDim.x == 2) {
    int lin = bxx + 2 * (byy + gridDim.y * bzz);
    bxx = (lin >> 3) & 1;
    int q = (lin & 7) | ((lin >> 4) << 3);
    byy = q % gridDim.y;
    bzz = q / gridDim.y;
  }
  const int tileM = byy * BM;
  const int tileN = bxx * BN;
  const int kper = K / ksplit;
  const int kbeg = bzz * kper;
  const int kend = kbeg + kper;

  const int srow = wave * 8 + (lane >> 3);
  const int sdst = (lane & 7) * 8;
  const int ssrc = ((lane & 7) ^ (lane >> 3)) * 8;

  f32x4 acc[4][4] = {};

  const u16* Arow = A + (size_t)tileM * K;
  const u16* Brow = B + (size_t)tileN * K;

  for (int kt = kbeg; kt < kend; kt += BK) {
    __syncthreads();
#pragma unroll
    for (int r = 0; r < 4; ++r) {
      int row = r * 32 + srow;
      gload16(Arow + (size_t)row * K + kt + ssrc, &As[row * BK + sdst]);
      gload16(Brow + (size_t)row * K + kt + ssrc, &Bs[row * BK + sdst]);
    }
    __syncthreads();
#pragma unroll
    for (int ks = 0; ks < 2; ++ks) {
      short8 af[4], bfq[4];
#pragma unroll
      for (int m = 0; m < 4; ++m)
        af[m] = *(const short8*)&As[(wr * 64 + m * 16 + (lane & 15)) * BK
                 + ((((ks << 2) | (lane >> 4)) ^ (lane & 7)) << 3)];
#pragma unroll
      for (int n = 0; n < 4; ++n)
        bfq[n] = *(const short8*)&Bs[(wc * 64 + n * 16 + (lane & 15)) * BK
                 + ((((ks << 2) | (lane >> 4)) ^ (lane & 7)) << 3)];
#pragma unroll
      for (int m = 0; m < 4; ++m)
#pragma unroll
        for (int n = 0; n < 4; ++n)
          acc[m][n] = __builtin_amdgcn_mfma_f32_16x16x32_bf16(af[m], bfq[n], acc[m][n], 0, 0, 0);
    }
  }

  if constexpr (EPI == 3) {
    // --- fused G1 epilogue: transpose in LDS, write fwlinT/fvT + fvb8 ---
    __syncthreads();                       // done with As/Bs
    const int lr0 = wr * 64 + ((lane >> 4) << 2);
    const int lc0 = wc * 64 + (lane & 15);
#pragma unroll
    for (int m = 0; m < 4; ++m) {
#pragma unroll
      for (int j = 0; j < 4; ++j) {
        const int lr = lr0 + m * 16 + j;
#pragma unroll
        for (int n = 0; n < 4; ++n) {
          const int lc = lc0 + n * 16;
          sh[lr * 128 + ((((lc >> 3) ^ (lr & 7)) << 3) | (lc & 7))] = f2bf(acc[m][n][j]);
        }
      }
    }
    __syncthreads();
    // transposed coalesced write: row th = tid>>1, v-segment = (tid&1)*64
    {
      const int th = tid >> 1;
      const int seg = (tid & 1) * 64;
      u16* oT = (tileN < 256) ? fwlinT : fvT;
      const int hb = (tileN < 256) ? tileN : tileN - 256;
      u16* dst = oT + (size_t)(hb + th) * V_N + tileM + seg;
      short8 buf[8];
#pragma unroll
      for (int c8 = 0; c8 < 8; ++c8) {
#pragma unroll
        for (int e = 0; e < 8; ++e) {
          const int lr = seg + c8 * 8 + e;
          ((u16*)&buf[c8])[e] = sh[lr * 128 + ((((th >> 3) ^ (lr & 7)) << 3) | (th & 7))];
        }
      }
#pragma unroll
      for (int c8 = 0; c8 < 8; ++c8) ((short8*)dst)[c8] = buf[c8];
    }
    // fp8-pi pack of fv (cols 256..511)
    if (tileN >= 256) {
      const int v = tid >> 1;
      const int half = tid & 1;
#pragma unroll
      for (int c = 0; c < 8; ++c) {
        const int lc = half * 64 + c * 8;
        const u16* src = &sh[v * 128 + (((lc >> 3) ^ (v & 7)) << 3)];
        float f[8];
#pragma unroll
        for (int e = 0; e < 8; ++e) f[e] = bf2f(src[e]);
        const int k0 = (tileN - 256) + lc;
        fvb8[(size_t)(tileM + v) * 32 + (pi8(k0) >> 3)] = pack8_fp8(f);
      }
    }
    return;
  }

  const int r0 = tileM + wr * 64 + ((lane >> 4) << 2);
  const int c0 = tileN + wc * 64 + (lane & 15);
  u16* oB = (EPI == 2) ? (outB + (size_t)bzz * sstride) : outB;
#pragma unroll
  for (int m = 0; m < 4; ++m) {
#pragma unroll
    for (int j = 0; j < 4; ++j) {
      const int row = r0 + m * 16 + j;
#pragma unroll
      for (int n = 0; n < 4; ++n) {
        const int col = c0 + n * 16;
        oB[(size_t)row * N + col] = f2bf(acc[m][n][j]);
      }
    }
  }
}

// ---------------- utility kernels ----------------

// merged prep: blocks 0..8191 = adj transpose + degree PARTIALS (no atomics);
// 8192..10239 = feats->bf16; 10240..11263 = Wcat transpose->bf16;
// 11264 = zero Dv/SWv/sums
__global__ void k_prep(const float* __restrict__ adj, const float* __restrict__ feats,
                       const float* __restrict__ Wl, const float* __restrict__ Wv,
                       u16* __restrict__ adjT, float* __restrict__ degP,
                       u16* __restrict__ featsb, u16* __restrict__ WT,
                       float* __restrict__ zreg) {
  __shared__ float t[32][33];
  int bx = blockIdx.x;
  if (bx < 8192) {
    int e0 = (bx & 63) * 32, v0 = (bx >> 6) * 32;
    int tx = threadIdx.x & 31, ty = threadIdx.x >> 5;
    for (int i = ty; i < 32; i += 8)
      t[i][tx] = adj[(size_t)(v0 + i) * E_N + e0 + tx];
    __syncthreads();
    for (int i = ty; i < 32; i += 8)
      adjT[(size_t)(e0 + i) * V_N + v0 + tx] = f2bf(t[tx][i]);
    if (ty == 0) {
      float s = 0.f;
#pragma unroll
      for (int i = 0; i < 32; ++i) s += t[i][tx];
      degP[(size_t)(v0 >> 5) * E_N + e0 + tx] = s;   // disjoint partial
    }
  } else if (bx < 10240) {
    int i = (bx - 8192) * 256 + threadIdx.x;
    float4 v = ((const float4*)feats)[i];
    ushort4 o; o.x = f2bf(v.x); o.y = f2bf(v.y); o.z = f2bf(v.z); o.w = f2bf(v.w);
    ((ushort4*)featsb)[i] = o;
  } else if (bx < 11264) {
    int id = (bx - 10240) * 256 + threadIdx.x;
    int n = id >> 9, k = id & 511;
    float v = (n < 256) ? Wl[(size_t)k * 256 + n] : Wv[(size_t)k * 256 + (n - 256)];
    WT[id] = f2bf(v);
  } else {
    if (threadIdx.x < 144) ((f32x4*)zreg)[threadIdx.x] = (f32x4){0.f, 0.f, 0.f, 0.f};
  }
}

// Fused dual LayerNorm over bf16 slice sums (8 slices each path).
// Divisor from partials: E-path = sum of 128 degP slices; V-path = 16 rsumP.
__global__ void k_ln8dual(const u16* __restrict__ XE8, const u16* __restrict__ XV8,
                          const float* __restrict__ degP, const float* __restrict__ rsumP,
                          const float* __restrict__ g1, const float* __restrict__ b1,
                          const float* __restrict__ g2, const float* __restrict__ b2,
                          const float* __restrict__ w,
                          u16* __restrict__ sw_b, u16* __restrict__ d_b,
                          float* __restrict__ aE, float* __restrict__ cV)
{
  __shared__ float sm[8];
  __shared__ float dsm[2];
  const int bid = blockIdx.x, tid = threadIdx.x, lane = tid & 63, wave = tid >> 6;
  const bool isE = bid < E_N;
  const int row = isE ? bid : bid - E_N;
  const u16* X = isE ? XE8 : XV8;
  const size_t sstr = isE ? (size_t)E_N * H_N : (size_t)V_N * H_N;
  const float* gg = isE ? g1 : g2;
  const float* bb = isE ? b1 : b2;
  u16* outB = isE ? sw_b : d_b;
  float* outA = isE ? aE : cV;

  const float* Pp = isE ? degP : rsumP;
  const int nP = isE ? 128 : 16;
  const int pstr = isE ? E_N : V_N;
  float pv = (tid < nP) ? Pp[(size_t)tid * pstr + row] : 0.f;
#pragma unroll
  for (int o = 32; o > 0; o >>= 1) pv += __shfl_down(pv, o);
  if (wave < 2 && lane == 0) dsm[wave] = pv;

  float x = 0.f;
#pragma unroll
  for (int s = 0; s < 8; ++s)
    x += bf2f(__builtin_nontemporal_load(&X[(size_t)s * sstr + (size_t)row * 256 + tid]));
  __syncthreads();
  x /= (dsm[0] + dsm[1]);
  float s1 = x, s2 = x * x;
#pragma unroll
  for (int o = 32; o > 0; o >>= 1) { s1 += __shfl_down(s1, o); s2 += __shfl_down(s2, o); }
  if (lane == 0) { sm[wave] = s1; sm[4 + wave] = s2; }
  __syncthreads();
  float sx  = sm[0] + sm[1] + sm[2] + sm[3];
  float sx2 = sm[4] + sm[5] + sm[6] + sm[7];
  float mu  = sx * (1.f / 256.f);
  float var = sx2 * (1.f / 256.f) - mu * mu;
  float rs  = rsqrtf(var + 1e-5f);
  float xln = (x - mu) * rs * gg[tid] + bb[tid];
  outB[(size_t)row * 256 + tid] = f2bf(isE ? xln * w[tid] : xln);
  float t = w[tid] * xln * xln;
  __syncthreads();
#pragma unroll
  for (int o = 32; o > 0; o >>= 1) t += __shfl_down(t, o);
  if (lane == 0) sm[wave] = t;
  __syncthreads();
  if (tid == 0) outA[row] = sm[0] + sm[1] + sm[2] + sm[3];
}

// H-stats, stage 1: D[h] = sum_v d[v][h], SW[h] = sum_e sw[e][h],
// sums[0] = sum aE, sums[1] = sum cV. (targets zeroed by k_prep)
__global__ void k_hstats(const u16* __restrict__ d_b, const u16* __restrict__ sw_b,
                         const float* __restrict__ aE, const float* __restrict__ cV,
                         float* __restrict__ D, float* __restrict__ SW,
                         float* __restrict__ sums) {
  int b = blockIdx.x, tid = threadIdx.x;
  if (b < 16) {
    float acc = 0.f;
    const u16* p = d_b + (size_t)b * 256 * 256 + tid;
    for (int r = 0; r < 256; ++r) acc += bf2f(__builtin_nontemporal_load(&p[r * 256]));
    atomicAdd(&D[tid], acc);
  } else if (b < 24) {
    float acc = 0.f;
    const u16* p = sw_b + (size_t)(b - 16) * 256 * 256 + tid;
    for (int r = 0; r < 256; ++r) acc += bf2f(__builtin_nontemporal_load(&p[r * 256]));
    atomicAdd(&SW[tid], acc);
  } else {
    const float* src = (b == 24) ? aE : cV;
    const int n = (b == 24) ? E_N : V_N;
    float s = 0.f;
    for (int i = tid; i < n; i += 256) s += src[i];
#pragma unroll
    for (int o = 32; o > 0; o >>= 1) s += __shfl_down(s, o);
    if ((tid & 63) == 0) atomicAdd(&sums[b - 24], s);
  }
}

// H-stats, stage 2 (linearized H): blocks 0..V-1: DV/uv/udv per row.
// Block V: closed-form S and scal[] for k_blend.
__global__ void k_dvde(const u16* __restrict__ d_b,
                       const float* __restrict__ cV,
                       const float* __restrict__ D, const float* __restrict__ SW,
                       const float* __restrict__ sums, const float* __restrict__ biasp,
                       const int* __restrict__ sigmap, const int* __restrict__ num,
                       float* __restrict__ DV,
                       float* __restrict__ uv, float* __restrict__ udv,
                       float* __restrict__ scal) {
  __shared__ float sm[4];
  const int b = blockIdx.x, tid = threadIdx.x, lane = tid & 63, wave = tid >> 6;
  float x;
  if (b < V_N) {
    x = bf2f(__builtin_nontemporal_load(&d_b[(size_t)b * 256 + tid])) * SW[tid];
  } else {
    x = SW[tid] * D[tid];
  }
#pragma unroll
  for (int o = 32; o > 0; o >>= 1) x += __shfl_down(x, o);
  if (lane == 0) sm[wave] = x;
  __syncthreads();
  if (tid == 0) {
    const float dot = sm[0] + sm[1] + sm[2] + sm[3];
    const float sgm = (float)sigmap[0];
    const float i2s = 1.f / (2.f * sgm * sgm);
    const float bias = biasp[0];
    if (b < V_N) {
      float dv = (float)E_N - i2s * (sums[0] + (float)E_N * (cV[b] + bias) - 2.f * dot);
      DV[b] = dv;
      float u = rsqrtf(dv);
      uv[b] = u;
      udv[b] = u * dv;            // = sqrt(dv)
    } else {
      const float T = (float)V_N * (sums[0] + (float)E_N * bias)
                    + (float)E_N * sums[1] - 2.f * dot;
      const float S = (float)E_N / (float)V_N
                    + i2s * T / ((float)V_N * (float)V_N);
      const float theta = theta_of(num[0]);
      scal[0] = 1.f - theta;
      scal[1] = theta * S * (1.f / (float)E_N);
    }
  }
}

// out[i,j] = scal0*G + C0*uv[j] + C1*udv[j];  C1 = scal1*uv_i, C0 = C1*(DV_i-E).
// NONTEMPORAL loads on G (bypass slow L3-hit path; proven round 17) + nt stores.
__global__ __launch_bounds__(256)
void k_blend(const float* __restrict__ G, const float* __restrict__ DV,
             const float* __restrict__ uv, const float* __restrict__ udv,
             const float* __restrict__ scal, float* __restrict__ out) {
  const int tid = threadIdx.x;
  const float omt = scal[0], tk = scal[1];
  const int row0 = blockIdx.x * 8;

  f32x4 uu[4], dd[4];
  const f32x4* u4 = (const f32x4*)uv;
  const f32x4* ud4 = (const f32x4*)udv;
#pragma unroll
  for (int c4 = 0; c4 < 4; ++c4) {
    uu[c4] = u4[c4 * 256 + tid];
    dd[c4] = ud4[c4 * 256 + tid];
  }

#pragma unroll
  for (int rr = 0; rr < 8; ++rr) {
    const int row = row0 + rr;
    const float uvi = uv[row];
    const float C1 = tk * uvi;
    const float C0 = C1 * (DV[row] - (float)E_N);
    const f32x4* g4 = (const f32x4*)(G + (size_t)row * V_N);
    f32x4* o4 = (f32x4*)(out + (size_t)row * V_N);
#pragma unroll
    for (int c4 = 0; c4 < 4; ++c4) {
      const int c = c4 * 256 + tid;
      f32x4 g = __builtin_nontemporal_load(&g4[c]);
      f32x4 o;
      o.x = omt * g.x + C0 * uu[c4].x + C1 * dd[c4].x;
      o.y = omt * g.y + C0 * uu[c4].y + C1 * dd[c4].y;
      o.z = omt * g.z + C0 * uu[c4].z + C1 * dd[c4].z;
      o.w = omt * g.w + C0 * uu[c4].w + C1 * dd[c4].w;
      __builtin_nontemporal_store(o, &o4[c]);
    }
  }
}

// ---------------- host ----------------

extern "C" void kernel_launch(void* const* d_in, const int* in_sizes, int n_in,
                              void* d_out, int out_size, void* d_ws, size_t ws_size,
                              hipStream_t stream)
{
  const float* adj   = (const float*)d_in[0];
  const float* G     = (const float*)d_in[1];
  const float* feats = (const float*)d_in[2];
  const float* Wl    = (const float*)d_in[3];
  const float* Wv    = (const float*)d_in[4];
  const float* wo_w  = (const float*)d_in[5];
  const float* wo_b  = (const float*)d_in[6];
  const float* g1    = (const float*)d_in[7];
  const float* b1    = (const float*)d_in[8];
  const float* g2    = (const float*)d_in[9];
  const float* b2    = (const float*)d_in[10];
  const int*   num   = (const int*)d_in[11];
  const int*   sigma = (const int*)d_in[12];
  float* out = (float*)d_out;

  hipFuncSetAttribute((const void*)gemm_nt_big8, hipFuncAttributeMaxDynamicSharedMemorySize, 65536);

  char* w = (char*)d_ws;
  auto take = [&](size_t b) { void* p = (void*)w; w += (b + 255) & ~(size_t)255; return p; };
  // zero-region (zeroed by k_prep block 11264): Dv, SWv, sums (contiguous)
  float* Dv    = (float*)take(256 * 4);
  float* SWv   = (float*)take(256 * 4);
  float* sums  = (float*)take(256);
  // partial-sum buffers (every slot written before read - no zeroing):
  float* degP  = (float*)take((size_t)128 * E_N * 4);   // 1 MB
  float* rsumP = (float*)take((size_t)16 * V_N * 4);    // 256 KB
  // written-not-accumulated:
  float* aE    = (float*)take(E_N * 4);
  float* cV    = (float*)take(V_N * 4);
  float* DV    = (float*)take(V_N * 4);
  float* uvv   = (float*)take(V_N * 4);
  float* udvv  = (float*)take(V_N * 4);
  float* scal  = (float*)take(256);
  // big0 (20.5 MB): featsb + WcatT + adjTb; later: d_mat8 (8 slices x V x H bf16)
  char* big0   = (char*)take((size_t)V_N * F_N * 2 + 512 * 512 * 2 + (size_t)E_N * V_N * 2);
  u16* featsb  = (u16*)big0;
  u16* WcatT   = (u16*)(big0 + (size_t)V_N * F_N * 2);
  u16* adjTb   = (u16*)(big0 + (size_t)V_N * F_N * 2 + 512 * 512 * 2);
  u16* d_mat8  = (u16*)big0;
  // big1 (8 MB): s_raw8 (8 slices x E x H bf16)
  char* big1   = (char*)take((size_t)8 * E_N * H_N * 2 + 256);
  u16* s_raw8  = (u16*)big1;
  u16* fwlinT  = (u16*)take((size_t)H_N * V_N * 2);
  u16* fvT     = (u16*)take((size_t)H_N * V_N * 2);
  ull* fvb8    = (ull*)take((size_t)V_N * H_N);
  u16* sw_b    = (u16*)take((size_t)E_N * H_N * 2);
  u16* d_b     = (u16*)take((size_t)V_N * H_N * 2);
  u16* expsb   = (u16*)take((size_t)V_N * V_N * 2);
  (void)in_sizes; (void)n_in; (void)out_size;
  if ((size_t)(w - (char*)d_ws) > ws_size) return;

  // prep: adj transpose + degree partials, feats->bf16, Wcat transpose, zero
  k_prep<<<11265, 256, 0, stream>>>(adj, feats, Wl, Wv, adjTb, degP, featsb, WcatT, Dv);

  // G1 (fused): bf16(feats @ [W_lin|W_v]) -> fwlinT/fvT transposed + fvb8 fp8
  gemm_nt<3><<<dim3(512 / BN, V_N / BM), 256, 0, stream>>>(
      featsb, WcatT, V_N, 512, 512, 1, 0, nullptr, fwlinT, fvT, fvb8);

  // G2: s_raw8 slices = adj.T @ fwlin   (M=E, N=H, K=V, split-K 8, bf16 slices)
  gemm_nt<2><<<dim3(H_N / BN, E_N / BM, 8), 256, 0, stream>>>(
      adjTb, fwlinT, E_N, H_N, V_N, 8, (size_t)E_N * H_N, s_raw8,
      nullptr, nullptr, nullptr);

  // G3: expsb = exp(fv @ fv.T / 16)  (fp8 in, bf16 out) + row-sum partials
  gemm_nt_big8<<<dim3(V_N / 256, V_N / 256), 512, 65536, stream>>>(
      (const u8*)fvb8, (const u8*)fvb8, V_N, H_N, 0.0625f,
      expsb, rsumP);

  // G4: P slices = expS @ fv   (M=V, N=H, K=V, split-K 8, bf16 slices)
  gemm_nt<2><<<dim3(H_N / BN, V_N / BM, 8), 256, 0, stream>>>(
      expsb, fvT, V_N, H_N, V_N, 8, (size_t)V_N * H_N, d_mat8,
      nullptr, nullptr, nullptr);

  // fused dual LayerNorm (divisors reduced from degP / rsumP partials)
  k_ln8dual<<<E_N + V_N, 256, 0, stream>>>(s_raw8, d_mat8, degP, rsumP,
                                           g1, b1, g2, b2, wo_w,
                                           sw_b, d_b, aE, cV);

  // linearized H statistics + closed-form S/theta scalars
  k_hstats<<<26, 256, 0, stream>>>(d_b, sw_b, aE, cV, Dv, SWv, sums);
  k_dvde<<<V_N + 1, 256, 0, stream>>>(d_b, cV, Dv, SWv, sums,
                                      wo_b, sigma, num, DV, uvv, udvv, scal);

  // out = (1-theta)*G + theta*u_i*u_j*(S + t_i + t_j)  (rank-structure G6)
  k_blend<<<V_N / 8, 256, 0, stream>>>(G, DV, uvv, udvv, scal, out);
}